// Round 9
// baseline (266.116 us; speedup 1.0000x reference)
//
#include <hip/hip_runtime.h>

typedef short short8 __attribute__((ext_vector_type(8)));
typedef float f32x4 __attribute__((ext_vector_type(4)));
typedef float f32x16 __attribute__((ext_vector_type(16)));
typedef unsigned short u16x4 __attribute__((ext_vector_type(4)));
typedef unsigned uint4v __attribute__((ext_vector_type(4)));

#define DEV static __device__ __forceinline__

DEV float b2f(unsigned short u) { return __uint_as_float(((unsigned)u) << 16); }
DEV unsigned short f2b(float f) {
    unsigned u = __float_as_uint(f);
    u += 0x7FFFu + ((u >> 16) & 1u);
    return (unsigned short)(u >> 16);
}
DEV unsigned pack2(float a, float b) {
    return (unsigned)f2b(a) | ((unsigned)f2b(b) << 16);
}
DEV unsigned cvtpk(float lo, float hi) {
    unsigned r;
    asm("v_cvt_pk_bf16_f32 %0, %1, %2" : "=v"(r) : "v"(lo), "v"(hi));
    return r;
}
DEV float wred_sum(float v) {
#pragma unroll
    for (int o = 32; o; o >>= 1) v += __shfl_xor(v, o);
    return v;
}
DEV float fast_exp2(float x) { return __builtin_exp2f(x); }

DEV void gld_lds16(const unsigned short* g, unsigned short* l) {
    __builtin_amdgcn_global_load_lds((const __attribute__((address_space(1))) void*)g,
                                     (__attribute__((address_space(3))) void*)l, 16, 0, 0);
}

// ---------------- LayerNorm ----------------
template <bool OUT_BF16>
__global__ __launch_bounds__(256) void ln_kernel(const float* __restrict__ in,
                                                 void* __restrict__ out_v,
                                                 const float* __restrict__ alpha_p,
                                                 const float* __restrict__ bias_p) {
    __shared__ float redA[4], redB[4];
    const int row = blockIdx.x;
    const int t = threadIdx.x;
    const int lane = t & 63, w = t >> 6;

    f32x4 xv = *(const f32x4*)&in[(size_t)row * 1024 + t * 4];

    float s = wred_sum(xv[0] + xv[1] + xv[2] + xv[3]);
    if (lane == 0) redA[w] = s;
    __syncthreads();
    float mean = (redA[0] + redA[1] + redA[2] + redA[3]) * (1.0f / 1024.0f);

    float d0 = xv[0] - mean, d1 = xv[1] - mean, d2 = xv[2] - mean, d3 = xv[3] - mean;
    float ss = wred_sum(d0 * d0 + d1 * d1 + d2 * d2 + d3 * d3);
    if (lane == 0) redB[w] = ss;
    __syncthreads();
    float var = (redB[0] + redB[1] + redB[2] + redB[3]) * (1.0f / 1023.0f);
    float denom = sqrtf(var) + 1e-9f;
    float inv = alpha_p[0] / denom;
    float bias = bias_p[0];

    if (OUT_BF16) {
        u16x4 o;
        o[0] = f2b(d0 * inv + bias);
        o[1] = f2b(d1 * inv + bias);
        o[2] = f2b(d2 * inv + bias);
        o[3] = f2b(d3 * inv + bias);
        *(u16x4*)&((unsigned short*)out_v)[(size_t)row * 1024 + t * 4] = o;
    } else {
        f32x4 o;
        o[0] = d0 * inv + bias;
        o[1] = d1 * inv + bias;
        o[2] = d2 * inv + bias;
        o[3] = d3 * inv + bias;
        *(f32x4*)&((float*)out_v)[(size_t)row * 1024 + t * 4] = o;
    }
}

// ---------------- f32 -> bf16 transpose ----------------
__global__ __launch_bounds__(256) void transpose_cast_kernel(const float* __restrict__ in,
                                                             unsigned short* __restrict__ out,
                                                             int R, int C) {
    __shared__ unsigned short tile[32][33];
    const int c0 = blockIdx.x * 32, r0 = blockIdx.y * 32;
    const int x = threadIdx.x, y0 = threadIdx.y;
#pragma unroll
    for (int yy = y0; yy < 32; yy += 8) tile[yy][x] = f2b(in[(size_t)(r0 + yy) * C + c0 + x]);
    __syncthreads();
#pragma unroll
    for (int yy = y0; yy < 32; yy += 8) out[(size_t)(c0 + yy) * R + r0 + x] = tile[x][yy];
}

// ---------------- bf16 [b][s][d] -> [b][d][s] transpose ----------------
__global__ __launch_bounds__(256) void transpose_bf16_batch(const unsigned short* __restrict__ in,
                                                            unsigned short* __restrict__ out) {
    __shared__ unsigned short tile[32][33];
    const int b = blockIdx.z;
    const int d0 = blockIdx.x * 32, s0 = blockIdx.y * 32;
    const unsigned short* I = in + (size_t)b * 1024 * 1024;
    unsigned short* O = out + (size_t)b * 1024 * 1024;
    const int x = threadIdx.x, y0 = threadIdx.y;
#pragma unroll
    for (int yy = y0; yy < 32; yy += 8) tile[yy][x] = I[(size_t)(s0 + yy) * 1024 + d0 + x];
    __syncthreads();
#pragma unroll
    for (int yy = y0; yy < 32; yy += 8) O[(size_t)(d0 + yy) * 1024 + s0 + x] = tile[x][yy];
}

// ---------------- GEMM v2 (unchanged): global_load_lds, BK=64, XOR swizzle ----------------
template <int BM, int BN, bool RELU, bool RES, bool OUT_BF16>
__global__ __launch_bounds__(256) void gemm2(const unsigned short* __restrict__ A,
                                             const unsigned short* __restrict__ Bt,
                                             const float* __restrict__ bias,
                                             const float* __restrict__ res,
                                             void* __restrict__ C_v,
                                             int M, int N, int K) {
    constexpr int WM = BM / 2, WN = BN / 2;
    constexpr int FM = WM / 16, FN = WN / 16;
    __shared__ __align__(16) unsigned short As[BM * 64];
    __shared__ __align__(16) unsigned short Bs[BN * 64];

    const int t = threadIdx.x;
    const int lane = t & 63, w = t >> 6;
    const int wr = w >> 1, wc = w & 1;
    const int lr = lane & 15, g = lane >> 4;

    const int nwg = gridDim.x;
    const int cpx = nwg >> 3;
    const int wg = blockIdx.x;
    const int swz = (wg & 7) * cpx + (wg >> 3);
    const int NB = N / BN;
    const int m0 = (swz / NB) * BM, n0 = (swz % NB) * BN;

    f32x4 acc[FM][FN];
#pragma unroll
    for (int i = 0; i < FM; ++i)
#pragma unroll
        for (int j = 0; j < FN; ++j) acc[i][j] = (f32x4)0.0f;

    for (int k0 = 0; k0 < K; k0 += 64) {
        __syncthreads();
#pragma unroll
        for (int i = 0; i < BM / 32; ++i) {
            int id = i * 256 + t;
            int row = id >> 3, ch = id & 7;
            gld_lds16(&A[(size_t)(m0 + row) * K + k0 + ((ch ^ (row & 7)) * 8)],
                      &As[(size_t)(i * 256 + (t & ~63)) * 8]);
        }
#pragma unroll
        for (int i = 0; i < BN / 32; ++i) {
            int id = i * 256 + t;
            int row = id >> 3, ch = id & 7;
            gld_lds16(&Bt[(size_t)(n0 + row) * K + k0 + ((ch ^ (row & 7)) * 8)],
                      &Bs[(size_t)(i * 256 + (t & ~63)) * 8]);
        }
        __syncthreads();

        short8 af[FM][2], bfr[FN][2];
#pragma unroll
        for (int mi = 0; mi < FM; ++mi) {
            int row = wr * WM + mi * 16 + lr;
#pragma unroll
            for (int ks = 0; ks < 2; ++ks) {
                int ch = (ks * 4 + g) ^ (row & 7);
                af[mi][ks] = *(const short8*)&As[row * 64 + ch * 8];
            }
        }
#pragma unroll
        for (int ni = 0; ni < FN; ++ni) {
            int row = wc * WN + ni * 16 + lr;
#pragma unroll
            for (int ks = 0; ks < 2; ++ks) {
                int ch = (ks * 4 + g) ^ (row & 7);
                bfr[ni][ks] = *(const short8*)&Bs[row * 64 + ch * 8];
            }
        }
#pragma unroll
        for (int ks = 0; ks < 2; ++ks)
#pragma unroll
            for (int mi = 0; mi < FM; ++mi)
#pragma unroll
                for (int ni = 0; ni < FN; ++ni)
                    acc[mi][ni] = __builtin_amdgcn_mfma_f32_16x16x32_bf16(af[mi][ks], bfr[ni][ks], acc[mi][ni], 0, 0, 0);
    }

    const int lg = g;
#pragma unroll
    for (int ni = 0; ni < FN; ++ni) {
        int col = n0 + wc * WN + ni * 16 + lr;
        float bv = bias[col];
#pragma unroll
        for (int mi = 0; mi < FM; ++mi) {
            int row0 = m0 + wr * WM + mi * 16 + lg * 4;
#pragma unroll
            for (int i = 0; i < 4; ++i) {
                int row = row0 + i;
                float x = acc[mi][ni][i] + bv;
                if (RES) x += res[(size_t)row * N + col];
                if (RELU) x = fmaxf(x, 0.0f);
                if (OUT_BF16)
                    ((unsigned short*)C_v)[(size_t)row * N + col] = f2b(x);
                else
                    ((float*)C_v)[(size_t)row * N + col] = x;
            }
        }
    }
}

// ---------------- MFMA flash attention v6: intra-block key-split + LDS combine ----------
// Block = 4 waves over the SAME 32 q-rows; wave w owns keys [w*256, w*256+256) (8 steps).
// Per wave: swapped QK^T (32x32x16), lane-local softmax (defer-max, base-2), cvt_pk pack,
// shfl-exchange -> PV B-frag, O^T accumulate. Epilogue: waves dump unnormalized O^T (bf16)
// + (m,l) to LDS; one barrier; 256 threads do the flash-decode combine and store coalesced.
// Grid (64 bh, 32 qt) = 2048 blocks -> ~32 waves/CU offered (was 8: grid-starved).
__global__ __launch_bounds__(256) void attn_part(const unsigned short* __restrict__ p,
                                                 const unsigned short* __restrict__ pT,
                                                 unsigned short* __restrict__ out) {
    __shared__ unsigned OldsW[4][32][33];  // [wave][q][u32 word of 2 bf16]; 33-pad: stride 33%32=1
    __shared__ float MLf[4][2][32];        // [wave][{m,l}][q]

    const int t = threadIdx.x;
    const int lane = t & 63, w = t >> 6;
    const int ql = lane & 31, hi = lane >> 5;
    const int bh = blockIdx.x;   // 0..63 -> XCD = linear%8 = bh%8 (head-siblings share XCD)
    const int qt = blockIdx.y;   // 0..31
    const int b = bh >> 4, h = bh & 15;

    const unsigned short* Pm = p + (size_t)b * (1024 * 1024) + h * 64;
    const unsigned short* PT = pT + (size_t)b * (1024 * 1024) + (size_t)(h * 64) * 1024;

    const int q0 = qt * 32;

    // Q B-frags: lane supplies Q[q0+ql][d=16s+8hi .. +7]
    short8 qb[4];
#pragma unroll
    for (int s = 0; s < 4; ++s)
        qb[s] = *(const short8*)&Pm[(size_t)(q0 + ql) * 1024 + 16 * s + 8 * hi];

    f32x16 oacc0 = (f32x16)0.0f, oacc1 = (f32x16)0.0f;  // O^T d-blocks 0..31 / 32..63
    float mrow = -1e30f;  // base-2 domain
    float lsum = 0.0f;    // lane-local

    const float C2 = 0.18033688011112042f;   // 0.125 * log2(e)
    const float THR2 = 11.541560327111708f;  // 8 * log2(e)

    for (int step = 0; step < 8; ++step) {
        const int key0 = w * 256 + step * 32;

        // QK^T (S^T): A = K rows (lane row = key0+ql), B = Q
        f32x16 sacc = (f32x16)0.0f;
#pragma unroll
        for (int s = 0; s < 4; ++s) {
            short8 ka = *(const short8*)&Pm[(size_t)(key0 + ql) * 1024 + 16 * s + 8 * hi];
            sacc = __builtin_amdgcn_mfma_f32_32x32x16_bf16(ka, qb[s], sacc, 0, 0, 0);
        }

        // V^T A-frags (independent of softmax; issue early)
        short8 va00 = *(const short8*)&PT[(size_t)ql * 1024 + key0 + 8 * hi];
        short8 va01 = *(const short8*)&PT[(size_t)ql * 1024 + key0 + 16 + 8 * hi];
        short8 va10 = *(const short8*)&PT[(size_t)(32 + ql) * 1024 + key0 + 8 * hi];
        short8 va11 = *(const short8*)&PT[(size_t)(32 + ql) * 1024 + key0 + 16 + 8 * hi];

        // lane-local row max + pair exchange
        float m01 = fmaxf(sacc[0], sacc[1]), m23 = fmaxf(sacc[2], sacc[3]);
        float m45 = fmaxf(sacc[4], sacc[5]), m67 = fmaxf(sacc[6], sacc[7]);
        float m89 = fmaxf(sacc[8], sacc[9]), mab = fmaxf(sacc[10], sacc[11]);
        float mcd = fmaxf(sacc[12], sacc[13]), mef = fmaxf(sacc[14], sacc[15]);
        float mx = fmaxf(fmaxf(fmaxf(m01, m23), fmaxf(m45, m67)),
                         fmaxf(fmaxf(m89, mab), fmaxf(mcd, mef)));
        mx = fmaxf(mx, __shfl_xor(mx, 32));
        float mx2 = mx * C2;

        float pf[16];
        bool defer = (mx2 <= mrow + THR2);
        if (__all(defer)) {
#pragma unroll
            for (int r = 0; r < 16; ++r) pf[r] = fast_exp2(fmaf(sacc[r], C2, -mrow));
        } else {
            float mnew = fmaxf(mrow, mx2);
            float scale = fast_exp2(mrow - mnew);
            mrow = mnew;
#pragma unroll
            for (int r = 0; r < 16; ++r) pf[r] = fast_exp2(fmaf(sacc[r], C2, -mnew));
            lsum *= scale;
#pragma unroll
            for (int r = 0; r < 16; ++r) { oacc0[r] *= scale; oacc1[r] *= scale; }
        }
        float ps = ((pf[0] + pf[1]) + (pf[2] + pf[3])) + ((pf[4] + pf[5]) + (pf[6] + pf[7])) +
                   (((pf[8] + pf[9]) + (pf[10] + pf[11])) + ((pf[12] + pf[13]) + (pf[14] + pf[15])));
        lsum += ps;

        // pack 16 f32 -> 8 bf16x2 words (v_cvt_pk); exchange halves to build PV B-frags
        unsigned wd0 = cvtpk(pf[0], pf[1]), wd1 = cvtpk(pf[2], pf[3]);
        unsigned wd2 = cvtpk(pf[4], pf[5]), wd3 = cvtpk(pf[6], pf[7]);
        unsigned wd4 = cvtpk(pf[8], pf[9]), wd5 = cvtpk(pf[10], pf[11]);
        unsigned wd6 = cvtpk(pf[12], pf[13]), wd7 = cvtpk(pf[14], pf[15]);

        unsigned x0 = (unsigned)__shfl_xor((int)wd0, 32);
        unsigned x1 = (unsigned)__shfl_xor((int)wd1, 32);
        unsigned x2 = (unsigned)__shfl_xor((int)wd2, 32);
        unsigned x3 = (unsigned)__shfl_xor((int)wd3, 32);
        unsigned x4 = (unsigned)__shfl_xor((int)wd4, 32);
        unsigned x5 = (unsigned)__shfl_xor((int)wd5, 32);
        unsigned x6 = (unsigned)__shfl_xor((int)wd6, 32);
        unsigned x7 = (unsigned)__shfl_xor((int)wd7, 32);

        union U8 { unsigned u[4]; short8 s; };
        U8 pb0, pb1;
        pb0.u[0] = hi ? x2 : wd0;
        pb0.u[1] = hi ? x3 : wd1;
        pb0.u[2] = hi ? wd2 : x0;
        pb0.u[3] = hi ? wd3 : x1;
        pb1.u[0] = hi ? x6 : wd4;
        pb1.u[1] = hi ? x7 : wd5;
        pb1.u[2] = hi ? wd6 : x4;
        pb1.u[3] = hi ? wd7 : x5;

        // PV: O^T[d][q] += V^T[d][k] * P^T[k][q]
        oacc0 = __builtin_amdgcn_mfma_f32_32x32x16_bf16(va00, pb0.s, oacc0, 0, 0, 0);
        oacc0 = __builtin_amdgcn_mfma_f32_32x32x16_bf16(va01, pb1.s, oacc0, 0, 0, 0);
        oacc1 = __builtin_amdgcn_mfma_f32_32x32x16_bf16(va10, pb0.s, oacc1, 0, 0, 0);
        oacc1 = __builtin_amdgcn_mfma_f32_32x32x16_bf16(va11, pb1.s, oacc1, 0, 0, 0);
    }

    // ---- dump per-wave partials to LDS ----
    lsum += __shfl_xor(lsum, 32);  // per-row chunk denominator (un-normalized)
    // O^T reg r -> d = (r&3) + 8*(r>>2) + 4*hi; pack consecutive-d pairs into u32 words
#pragma unroll
    for (int rq = 0; rq < 4; ++rq) {
#pragma unroll
        for (int pp = 0; pp < 2; ++pp) {
            int r = 4 * rq + 2 * pp;
            int wi = 4 * rq + 2 * hi + pp;
            OldsW[w][ql][wi] = cvtpk(oacc0[r], oacc0[r + 1]);
            OldsW[w][ql][16 + wi] = cvtpk(oacc1[r], oacc1[r + 1]);
        }
    }
    if (hi == 0) {
        MLf[w][0][ql] = mrow;
        MLf[w][1][ql] = lsum;
    }
    __syncthreads();

    // ---- combine: thread t -> row cql = t>>3, d-range dg..dg+7 ----
    const int cql = t >> 3;
    const int dg = (t & 7) * 8;
    float m0 = MLf[0][0][cql], m1 = MLf[1][0][cql], m2 = MLf[2][0][cql], m3 = MLf[3][0][cql];
    float mstar = fmaxf(fmaxf(m0, m1), fmaxf(m2, m3));
    float w0 = fast_exp2(m0 - mstar), w1 = fast_exp2(m1 - mstar);
    float w2 = fast_exp2(m2 - mstar), w3 = fast_exp2(m3 - mstar);
    float ltot = w0 * MLf[0][1][cql] + w1 * MLf[1][1][cql] +
                 w2 * MLf[2][1][cql] + w3 * MLf[3][1][cql];
    float inv = 1.0f / ltot;

    float o[8] = {0.f, 0.f, 0.f, 0.f, 0.f, 0.f, 0.f, 0.f};
    float wgt[4] = {w0, w1, w2, w3};
#pragma unroll
    for (int c = 0; c < 4; ++c) {
        float wc = wgt[c];
#pragma unroll
        for (int jw = 0; jw < 4; ++jw) {
            unsigned u = OldsW[c][cql][(dg >> 1) + jw];
            o[2 * jw] += wc * b2f((unsigned short)(u & 0xffff));
            o[2 * jw + 1] += wc * b2f((unsigned short)(u >> 16));
        }
    }
    unsigned short* O = out + (size_t)b * (1024 * 1024) + h * 64;
    uint4v v;
    v[0] = pack2(o[0] * inv, o[1] * inv);
    v[1] = pack2(o[2] * inv, o[3] * inv);
    v[2] = pack2(o[4] * inv, o[5] * inv);
    v[3] = pack2(o[6] * inv, o[7] * inv);
    *(uint4v*)&O[(size_t)(q0 + cql) * 1024 + dg] = v;
}

// ---------------- launch ----------------
extern "C" void kernel_launch(void* const* d_in, const int* in_sizes, int n_in,
                              void* d_out, int out_size, void* d_ws, size_t ws_size,
                              hipStream_t stream) {
    const float* x = (const float*)d_in[0];
    const float* wq_w = (const float*)d_in[1];
    const float* wq_b = (const float*)d_in[2];
    const float* wo_w = (const float*)d_in[3];
    const float* wo_b = (const float*)d_in[4];
    const float* ff1_w = (const float*)d_in[5];
    const float* ff1_b = (const float*)d_in[6];
    const float* ff2_w = (const float*)d_in[7];
    const float* ff2_b = (const float*)d_in[8];
    const float* alpha1 = (const float*)d_in[9];
    const float* bias1 = (const float*)d_in[10];
    const float* alpha2 = (const float*)d_in[11];
    const float* bias2 = (const float*)d_in[12];
    const float* alpha3 = (const float*)d_in[13];
    const float* bias3 = (const float*)d_in[14];
    float* out = (float*)d_out;

    const size_t MB = 1u << 20;
    char* ws = (char*)d_ws;
    unsigned short* wq_t = (unsigned short*)(ws + 0 * MB);
    unsigned short* wo_t = (unsigned short*)(ws + 2 * MB);
    unsigned short* ff1_t = (unsigned short*)(ws + 4 * MB);
    unsigned short* ff2_t = (unsigned short*)(ws + 12 * MB);
    unsigned short* lnbuf = (unsigned short*)(ws + 20 * MB);
    unsigned short* pbuf = (unsigned short*)(ws + 28 * MB);
    unsigned short* attn = (unsigned short*)(ws + 36 * MB);
    float* h1 = (float*)(ws + 44 * MB);
    unsigned short* pbT = (unsigned short*)(ws + 60 * MB);
    unsigned short* mid = (unsigned short*)(ws + 60 * MB);
    float* h2 = (float*)(ws + 28 * MB);

    const int M = 4096;

    transpose_cast_kernel<<<dim3(32, 32), dim3(32, 8), 0, stream>>>(wq_w, wq_t, 1024, 1024);
    transpose_cast_kernel<<<dim3(32, 32), dim3(32, 8), 0, stream>>>(wo_w, wo_t, 1024, 1024);
    transpose_cast_kernel<<<dim3(128, 32), dim3(32, 8), 0, stream>>>(ff1_w, ff1_t, 1024, 4096);
    transpose_cast_kernel<<<dim3(32, 128), dim3(32, 8), 0, stream>>>(ff2_w, ff2_t, 4096, 1024);

    ln_kernel<true><<<M, 256, 0, stream>>>(x, lnbuf, alpha1, bias1);
    gemm2<128, 64, false, false, true><<<512, 256, 0, stream>>>(lnbuf, wq_t, wq_b, nullptr, pbuf, M, 1024, 1024);
    transpose_bf16_batch<<<dim3(32, 32, 4), dim3(32, 8), 0, stream>>>(pbuf, pbT);
    attn_part<<<dim3(64, 32), 256, 0, stream>>>(pbuf, pbT, attn);
    gemm2<128, 64, false, true, false><<<512, 256, 0, stream>>>(attn, wo_t, wo_b, x, h1, M, 1024, 1024);
    ln_kernel<true><<<M, 256, 0, stream>>>(h1, lnbuf, alpha2, bias2);
    gemm2<128, 128, true, false, true><<<1024, 256, 0, stream>>>(lnbuf, ff1_t, ff1_b, nullptr, mid, M, 4096, 1024);
    gemm2<128, 64, false, true, false><<<512, 256, 0, stream>>>(mid, ff2_t, ff2_b, h1, h2, M, 1024, 4096);
    ln_kernel<false><<<M, 256, 0, stream>>>(h2, out, alpha3, bias3);
}

// Round 10
// 258.850 us; speedup vs baseline: 1.0281x; 1.0281x over previous
//
#include <hip/hip_runtime.h>

typedef short short8 __attribute__((ext_vector_type(8)));
typedef float f32x4 __attribute__((ext_vector_type(4)));
typedef unsigned short u16x4 __attribute__((ext_vector_type(4)));

#define DEV static __device__ __forceinline__

DEV float b2f(unsigned short u) { return __uint_as_float(((unsigned)u) << 16); }
DEV unsigned short f2b(float f) {
    unsigned u = __float_as_uint(f);
    u += 0x7FFFu + ((u >> 16) & 1u);
    return (unsigned short)(u >> 16);
}
DEV unsigned pack2(float a, float b) {
    return (unsigned)f2b(a) | ((unsigned)f2b(b) << 16);
}
DEV float wred_sum(float v) {
#pragma unroll
    for (int o = 32; o; o >>= 1) v += __shfl_xor(v, o);
    return v;
}

DEV void gld_lds16(const unsigned short* g, unsigned short* l) {
    __builtin_amdgcn_global_load_lds((const __attribute__((address_space(1))) void*)g,
                                     (__attribute__((address_space(3))) void*)l, 16, 0, 0);
}

// ---------------- LayerNorm ----------------
template <bool OUT_BF16>
__global__ __launch_bounds__(256) void ln_kernel(const float* __restrict__ in,
                                                 void* __restrict__ out_v,
                                                 const float* __restrict__ alpha_p,
                                                 const float* __restrict__ bias_p) {
    __shared__ float redA[4], redB[4];
    const int row = blockIdx.x;
    const int t = threadIdx.x;
    const int lane = t & 63, w = t >> 6;

    f32x4 xv = *(const f32x4*)&in[(size_t)row * 1024 + t * 4];

    float s = wred_sum(xv[0] + xv[1] + xv[2] + xv[3]);
    if (lane == 0) redA[w] = s;
    __syncthreads();
    float mean = (redA[0] + redA[1] + redA[2] + redA[3]) * (1.0f / 1024.0f);

    float d0 = xv[0] - mean, d1 = xv[1] - mean, d2 = xv[2] - mean, d3 = xv[3] - mean;
    float ss = wred_sum(d0 * d0 + d1 * d1 + d2 * d2 + d3 * d3);
    if (lane == 0) redB[w] = ss;
    __syncthreads();
    float var = (redB[0] + redB[1] + redB[2] + redB[3]) * (1.0f / 1023.0f);
    float denom = sqrtf(var) + 1e-9f;
    float inv = alpha_p[0] / denom;
    float bias = bias_p[0];

    if (OUT_BF16) {
        u16x4 o;
        o[0] = f2b(d0 * inv + bias);
        o[1] = f2b(d1 * inv + bias);
        o[2] = f2b(d2 * inv + bias);
        o[3] = f2b(d3 * inv + bias);
        *(u16x4*)&((unsigned short*)out_v)[(size_t)row * 1024 + t * 4] = o;
    } else {
        f32x4 o;
        o[0] = d0 * inv + bias;
        o[1] = d1 * inv + bias;
        o[2] = d2 * inv + bias;
        o[3] = d3 * inv + bias;
        *(f32x4*)&((float*)out_v)[(size_t)row * 1024 + t * 4] = o;
    }
}

// ---------------- f32 -> bf16 transpose ----------------
__global__ __launch_bounds__(256) void transpose_cast_kernel(const float* __restrict__ in,
                                                             unsigned short* __restrict__ out,
                                                             int R, int C) {
    __shared__ unsigned short tile[32][33];
    const int c0 = blockIdx.x * 32, r0 = blockIdx.y * 32;
    const int x = threadIdx.x, y0 = threadIdx.y;
#pragma unroll
    for (int yy = y0; yy < 32; yy += 8) tile[yy][x] = f2b(in[(size_t)(r0 + yy) * C + c0 + x]);
    __syncthreads();
#pragma unroll
    for (int yy = y0; yy < 32; yy += 8) out[(size_t)(c0 + yy) * R + r0 + x] = tile[x][yy];
}

// ---------------- bf16 [b][s][d] -> [b][d][s] transpose ----------------
__global__ __launch_bounds__(256) void transpose_bf16_batch(const unsigned short* __restrict__ in,
                                                            unsigned short* __restrict__ out) {
    __shared__ unsigned short tile[32][33];
    const int b = blockIdx.z;
    const int d0 = blockIdx.x * 32, s0 = blockIdx.y * 32;
    const unsigned short* I = in + (size_t)b * 1024 * 1024;
    unsigned short* O = out + (size_t)b * 1024 * 1024;
    const int x = threadIdx.x, y0 = threadIdx.y;
#pragma unroll
    for (int yy = y0; yy < 32; yy += 8) tile[yy][x] = I[(size_t)(s0 + yy) * 1024 + d0 + x];
    __syncthreads();
#pragma unroll
    for (int yy = y0; yy < 32; yy += 8) O[(size_t)(d0 + yy) * 1024 + s0 + x] = tile[x][yy];
}

// ---------------- GEMM v2 (unchanged): global_load_lds, BK=64, XOR swizzle ----------------
template <int BM, int BN, bool RELU, bool RES, bool OUT_BF16>
__global__ __launch_bounds__(256) void gemm2(const unsigned short* __restrict__ A,
                                             const unsigned short* __restrict__ Bt,
                                             const float* __restrict__ bias,
                                             const float* __restrict__ res,
                                             void* __restrict__ C_v,
                                             int M, int N, int K) {
    constexpr int WM = BM / 2, WN = BN / 2;
    constexpr int FM = WM / 16, FN = WN / 16;
    __shared__ __align__(16) unsigned short As[BM * 64];
    __shared__ __align__(16) unsigned short Bs[BN * 64];

    const int t = threadIdx.x;
    const int lane = t & 63, w = t >> 6;
    const int wr = w >> 1, wc = w & 1;
    const int lr = lane & 15, g = lane >> 4;

    const int nwg = gridDim.x;
    const int cpx = nwg >> 3;
    const int wg = blockIdx.x;
    const int swz = (wg & 7) * cpx + (wg >> 3);
    const int NB = N / BN;
    const int m0 = (swz / NB) * BM, n0 = (swz % NB) * BN;

    f32x4 acc[FM][FN];
#pragma unroll
    for (int i = 0; i < FM; ++i)
#pragma unroll
        for (int j = 0; j < FN; ++j) acc[i][j] = (f32x4)0.0f;

    for (int k0 = 0; k0 < K; k0 += 64) {
        __syncthreads();
#pragma unroll
        for (int i = 0; i < BM / 32; ++i) {
            int id = i * 256 + t;
            int row = id >> 3, ch = id & 7;
            gld_lds16(&A[(size_t)(m0 + row) * K + k0 + ((ch ^ (row & 7)) * 8)],
                      &As[(size_t)(i * 256 + (t & ~63)) * 8]);
        }
#pragma unroll
        for (int i = 0; i < BN / 32; ++i) {
            int id = i * 256 + t;
            int row = id >> 3, ch = id & 7;
            gld_lds16(&Bt[(size_t)(n0 + row) * K + k0 + ((ch ^ (row & 7)) * 8)],
                      &Bs[(size_t)(i * 256 + (t & ~63)) * 8]);
        }
        __syncthreads();

        short8 af[FM][2], bfr[FN][2];
#pragma unroll
        for (int mi = 0; mi < FM; ++mi) {
            int row = wr * WM + mi * 16 + lr;
#pragma unroll
            for (int ks = 0; ks < 2; ++ks) {
                int ch = (ks * 4 + g) ^ (row & 7);
                af[mi][ks] = *(const short8*)&As[row * 64 + ch * 8];
            }
        }
#pragma unroll
        for (int ni = 0; ni < FN; ++ni) {
            int row = wc * WN + ni * 16 + lr;
#pragma unroll
            for (int ks = 0; ks < 2; ++ks) {
                int ch = (ks * 4 + g) ^ (row & 7);
                bfr[ni][ks] = *(const short8*)&Bs[row * 64 + ch * 8];
            }
        }
#pragma unroll
        for (int ks = 0; ks < 2; ++ks)
#pragma unroll
            for (int mi = 0; mi < FM; ++mi)
#pragma unroll
                for (int ni = 0; ni < FN; ++ni)
                    acc[mi][ni] = __builtin_amdgcn_mfma_f32_16x16x32_bf16(af[mi][ks], bfr[ni][ks], acc[mi][ni], 0, 0, 0);
    }

    const int lg = g;
#pragma unroll
    for (int ni = 0; ni < FN; ++ni) {
        int col = n0 + wc * WN + ni * 16 + lr;
        float bv = bias[col];
#pragma unroll
        for (int mi = 0; mi < FM; ++mi) {
            int row0 = m0 + wr * WM + mi * 16 + lg * 4;
#pragma unroll
            for (int i = 0; i < 4; ++i) {
                int row = row0 + i;
                float x = acc[mi][ni][i] + bv;
                if (RES) x += res[(size_t)row * N + col];
                if (RELU) x = fmaxf(x, 0.0f);
                if (OUT_BF16)
                    ((unsigned short*)C_v)[(size_t)row * N + col] = f2b(x);
                else
                    ((float*)C_v)[(size_t)row * N + col] = x;
            }
        }
    }
}

// ---------------- MFMA flash attention (r4 best-known structure, bh-major grid) ----------
// Verbatim r4 kernel (66.6 us, VGPR 60, Occ 32%) with ONLY the grid axes swapped:
// bh on blockIdx.x so the 16 q-sibling blocks of one head land on one XCD (r5-proven
// FETCH 69->8 MB). LDS tiles XOR-swizzled both sides; per-wave P buffer; 2 barriers/tile.
__global__ __launch_bounds__(256) void attn_mfma_kernel(const unsigned short* __restrict__ p,
                                                        const unsigned short* __restrict__ pT,
                                                        unsigned short* __restrict__ out) {
    __shared__ __align__(16) unsigned short Ks[64 * 64];
    __shared__ __align__(16) unsigned short Vt[64 * 64];
    __shared__ __align__(16) unsigned short Ps[4 * 16 * 64];

    const int t = threadIdx.x;
    const int lane = t & 63, w = t >> 6;
    const int lr = lane & 15, g = lane >> 4;
    const int bh = blockIdx.x;     // 0..63 -> linear%8 = bh%8: head-siblings share XCD
    const int qblk = blockIdx.y;   // 0..15
    const int b = bh >> 4, h = bh & 15;

    const unsigned short* Pm = p + (size_t)b * (1024 * 1024) + h * 64;
    const unsigned short* PT = pT + (size_t)b * (1024 * 1024) + (size_t)(h * 64) * 1024;

    const int q0 = qblk * 64 + w * 16;
    short8 qa0 = *(const short8*)&Pm[(size_t)(q0 + lr) * 1024 + g * 8];
    short8 qa1 = *(const short8*)&Pm[(size_t)(q0 + lr) * 1024 + 32 + g * 8];

    f32x4 acc[4];
#pragma unroll
    for (int i = 0; i < 4; ++i) acc[i] = (f32x4)0.0f;
    float mrow[4] = {-1e30f, -1e30f, -1e30f, -1e30f};
    float lsum[4] = {0.f, 0.f, 0.f, 0.f};

    unsigned short* Pw = &Ps[w * 16 * 64];

    for (int kt = 0; kt < 16; ++kt) {
        const int key0 = kt * 64;
        __syncthreads();
#pragma unroll
        for (int i = 0; i < 2; ++i) {
            int id = t + i * 256;
            int row = id >> 3, ch = (id & 7) * 8;
            int sw = ch ^ ((row & 7) << 3);
            short8 kv = *(const short8*)&Pm[(size_t)(key0 + row) * 1024 + ch];
            *(short8*)&Ks[row * 64 + sw] = kv;
            short8 vv = *(const short8*)&PT[(size_t)row * 1024 + key0 + ch];
            *(short8*)&Vt[row * 64 + sw] = vv;
        }
        __syncthreads();

        f32x4 s_acc[4];
#pragma unroll
        for (int kg = 0; kg < 4; ++kg) {
            s_acc[kg] = (f32x4)0.0f;
            int krow = kg * 16 + lr;
            int swz = (krow & 7) << 3;
            short8 kb0 = *(const short8*)&Ks[krow * 64 + ((g * 8) ^ swz)];
            short8 kb1 = *(const short8*)&Ks[krow * 64 + ((32 + g * 8) ^ swz)];
            s_acc[kg] = __builtin_amdgcn_mfma_f32_16x16x32_bf16(qa0, kb0, s_acc[kg], 0, 0, 0);
            s_acc[kg] = __builtin_amdgcn_mfma_f32_16x16x32_bf16(qa1, kb1, s_acc[kg], 0, 0, 0);
        }

#pragma unroll
        for (int reg = 0; reg < 4; ++reg) {
            float mx = fmaxf(fmaxf(s_acc[0][reg], s_acc[1][reg]),
                             fmaxf(s_acc[2][reg], s_acc[3][reg])) * 0.125f;
            mx = fmaxf(mx, __shfl_xor(mx, 1));
            mx = fmaxf(mx, __shfl_xor(mx, 2));
            mx = fmaxf(mx, __shfl_xor(mx, 4));
            mx = fmaxf(mx, __shfl_xor(mx, 8));
            float mnew = fmaxf(mrow[reg], mx);
            float scale = __expf(mrow[reg] - mnew);
            mrow[reg] = mnew;
            float psum = 0.f;
#pragma unroll
            for (int kg = 0; kg < 4; ++kg) {
                float pv = __expf(s_acc[kg][reg] * 0.125f - mnew);
                s_acc[kg][reg] = pv;
                psum += pv;
            }
            psum += __shfl_xor(psum, 1);
            psum += __shfl_xor(psum, 2);
            psum += __shfl_xor(psum, 4);
            psum += __shfl_xor(psum, 8);
            lsum[reg] = lsum[reg] * scale + psum;
#pragma unroll
            for (int dg = 0; dg < 4; ++dg) acc[dg][reg] *= scale;
        }

#pragma unroll
        for (int reg = 0; reg < 4; ++reg) {
            int q = g * 4 + reg;
            int swz = (q & 7) << 3;
#pragma unroll
            for (int kg = 0; kg < 4; ++kg) {
                int key = lr + 16 * kg;
                Pw[q * 64 + (key ^ swz)] = f2b(s_acc[kg][reg]);
            }
        }
        int pswz = (lr & 7) << 3;
        short8 pa0 = *(const short8*)&Pw[lr * 64 + ((g * 8) ^ pswz)];
        short8 pa1 = *(const short8*)&Pw[lr * 64 + ((32 + g * 8) ^ pswz)];

#pragma unroll
        for (int dg = 0; dg < 4; ++dg) {
            int drow = dg * 16 + lr;
            int swz = (drow & 7) << 3;
            short8 vb0 = *(const short8*)&Vt[drow * 64 + ((g * 8) ^ swz)];
            short8 vb1 = *(const short8*)&Vt[drow * 64 + ((32 + g * 8) ^ swz)];
            acc[dg] = __builtin_amdgcn_mfma_f32_16x16x32_bf16(pa0, vb0, acc[dg], 0, 0, 0);
            acc[dg] = __builtin_amdgcn_mfma_f32_16x16x32_bf16(pa1, vb1, acc[dg], 0, 0, 0);
        }
    }

    unsigned short* O = out + (size_t)b * (1024 * 1024) + h * 64;
#pragma unroll
    for (int reg = 0; reg < 4; ++reg) {
        float inv = 1.0f / lsum[reg];
        int q = q0 + g * 4 + reg;
#pragma unroll
        for (int dg = 0; dg < 4; ++dg) {
            O[(size_t)q * 1024 + dg * 16 + lr] = f2b(acc[dg][reg] * inv);
        }
    }
}

// ---------------- launch ----------------
extern "C" void kernel_launch(void* const* d_in, const int* in_sizes, int n_in,
                              void* d_out, int out_size, void* d_ws, size_t ws_size,
                              hipStream_t stream) {
    const float* x = (const float*)d_in[0];
    const float* wq_w = (const float*)d_in[1];
    const float* wq_b = (const float*)d_in[2];
    const float* wo_w = (const float*)d_in[3];
    const float* wo_b = (const float*)d_in[4];
    const float* ff1_w = (const float*)d_in[5];
    const float* ff1_b = (const float*)d_in[6];
    const float* ff2_w = (const float*)d_in[7];
    const float* ff2_b = (const float*)d_in[8];
    const float* alpha1 = (const float*)d_in[9];
    const float* bias1 = (const float*)d_in[10];
    const float* alpha2 = (const float*)d_in[11];
    const float* bias2 = (const float*)d_in[12];
    const float* alpha3 = (const float*)d_in[13];
    const float* bias3 = (const float*)d_in[14];
    float* out = (float*)d_out;

    const size_t MB = 1u << 20;
    char* ws = (char*)d_ws;
    unsigned short* wq_t = (unsigned short*)(ws + 0 * MB);
    unsigned short* wo_t = (unsigned short*)(ws + 2 * MB);
    unsigned short* ff1_t = (unsigned short*)(ws + 4 * MB);
    unsigned short* ff2_t = (unsigned short*)(ws + 12 * MB);
    unsigned short* lnbuf = (unsigned short*)(ws + 20 * MB);
    unsigned short* pbuf = (unsigned short*)(ws + 28 * MB);
    unsigned short* attn = (unsigned short*)(ws + 36 * MB);
    float* h1 = (float*)(ws + 44 * MB);
    unsigned short* pbT = (unsigned short*)(ws + 60 * MB);
    unsigned short* mid = (unsigned short*)(ws + 60 * MB);
    float* h2 = (float*)(ws + 28 * MB);

    const int M = 4096;

    transpose_cast_kernel<<<dim3(32, 32), dim3(32, 8), 0, stream>>>(wq_w, wq_t, 1024, 1024);
    transpose_cast_kernel<<<dim3(32, 32), dim3(32, 8), 0, stream>>>(wo_w, wo_t, 1024, 1024);
    transpose_cast_kernel<<<dim3(128, 32), dim3(32, 8), 0, stream>>>(ff1_w, ff1_t, 1024, 4096);
    transpose_cast_kernel<<<dim3(32, 128), dim3(32, 8), 0, stream>>>(ff2_w, ff2_t, 4096, 1024);

    ln_kernel<true><<<M, 256, 0, stream>>>(x, lnbuf, alpha1, bias1);
    gemm2<128, 64, false, false, true><<<512, 256, 0, stream>>>(lnbuf, wq_t, wq_b, nullptr, pbuf, M, 1024, 1024);
    transpose_bf16_batch<<<dim3(32, 32, 4), dim3(32, 8), 0, stream>>>(pbuf, pbT);
    attn_mfma_kernel<<<dim3(64, 16), 256, 0, stream>>>(pbuf, pbT, attn);
    gemm2<128, 64, false, true, false><<<512, 256, 0, stream>>>(attn, wo_t, wo_b, x, h1, M, 1024, 1024);
    ln_kernel<true><<<M, 256, 0, stream>>>(h1, lnbuf, alpha2, bias2);
    gemm2<128, 128, true, false, true><<<1024, 256, 0, stream>>>(lnbuf, ff1_t, ff1_b, nullptr, mid, M, 4096, 1024);
    gemm2<128, 64, false, true, false><<<512, 256, 0, stream>>>(mid, ff2_t, ff2_b, h1, h2, M, 1024, 4096);
    ln_kernel<false><<<M, 256, 0, stream>>>(h2, out, alpha3, bias3);
}

// Round 11
// 254.512 us; speedup vs baseline: 1.0456x; 1.0170x over previous
//
#include <hip/hip_runtime.h>

typedef short short8 __attribute__((ext_vector_type(8)));
typedef float f32x4 __attribute__((ext_vector_type(4)));
typedef unsigned short u16x4 __attribute__((ext_vector_type(4)));

#define DEV static __device__ __forceinline__

DEV float b2f(unsigned short u) { return __uint_as_float(((unsigned)u) << 16); }
DEV unsigned short f2b(float f) {
    unsigned u = __float_as_uint(f);
    u += 0x7FFFu + ((u >> 16) & 1u);
    return (unsigned short)(u >> 16);
}
DEV float wred_sum(float v) {
#pragma unroll
    for (int o = 32; o; o >>= 1) v += __shfl_xor(v, o);
    return v;
}

DEV void gld_lds16(const unsigned short* g, unsigned short* l) {
    __builtin_amdgcn_global_load_lds((const __attribute__((address_space(1))) void*)g,
                                     (__attribute__((address_space(3))) void*)l, 16, 0, 0);
}

// ---------------- LayerNorm ----------------
template <bool OUT_BF16>
__global__ __launch_bounds__(256) void ln_kernel(const float* __restrict__ in,
                                                 void* __restrict__ out_v,
                                                 const float* __restrict__ alpha_p,
                                                 const float* __restrict__ bias_p) {
    __shared__ float redA[4], redB[4];
    const int row = blockIdx.x;
    const int t = threadIdx.x;
    const int lane = t & 63, w = t >> 6;

    f32x4 xv = *(const f32x4*)&in[(size_t)row * 1024 + t * 4];

    float s = wred_sum(xv[0] + xv[1] + xv[2] + xv[3]);
    if (lane == 0) redA[w] = s;
    __syncthreads();
    float mean = (redA[0] + redA[1] + redA[2] + redA[3]) * (1.0f / 1024.0f);

    float d0 = xv[0] - mean, d1 = xv[1] - mean, d2 = xv[2] - mean, d3 = xv[3] - mean;
    float ss = wred_sum(d0 * d0 + d1 * d1 + d2 * d2 + d3 * d3);
    if (lane == 0) redB[w] = ss;
    __syncthreads();
    float var = (redB[0] + redB[1] + redB[2] + redB[3]) * (1.0f / 1023.0f);
    float denom = sqrtf(var) + 1e-9f;
    float inv = alpha_p[0] / denom;
    float bias = bias_p[0];

    if (OUT_BF16) {
        u16x4 o;
        o[0] = f2b(d0 * inv + bias);
        o[1] = f2b(d1 * inv + bias);
        o[2] = f2b(d2 * inv + bias);
        o[3] = f2b(d3 * inv + bias);
        *(u16x4*)&((unsigned short*)out_v)[(size_t)row * 1024 + t * 4] = o;
    } else {
        f32x4 o;
        o[0] = d0 * inv + bias;
        o[1] = d1 * inv + bias;
        o[2] = d2 * inv + bias;
        o[3] = d3 * inv + bias;
        *(f32x4*)&((float*)out_v)[(size_t)row * 1024 + t * 4] = o;
    }
}

// ---------------- f32 -> bf16 transpose ----------------
__global__ __launch_bounds__(256) void transpose_cast_kernel(const float* __restrict__ in,
                                                             unsigned short* __restrict__ out,
                                                             int R, int C) {
    __shared__ unsigned short tile[32][33];
    const int c0 = blockIdx.x * 32, r0 = blockIdx.y * 32;
    const int x = threadIdx.x, y0 = threadIdx.y;
#pragma unroll
    for (int yy = y0; yy < 32; yy += 8) tile[yy][x] = f2b(in[(size_t)(r0 + yy) * C + c0 + x]);
    __syncthreads();
#pragma unroll
    for (int yy = y0; yy < 32; yy += 8) out[(size_t)(c0 + yy) * R + r0 + x] = tile[x][yy];
}

// ---------------- bf16 [b][s][d] -> [b][d][s] transpose ----------------
__global__ __launch_bounds__(256) void transpose_bf16_batch(const unsigned short* __restrict__ in,
                                                            unsigned short* __restrict__ out) {
    __shared__ unsigned short tile[32][33];
    const int b = blockIdx.z;
    const int d0 = blockIdx.x * 32, s0 = blockIdx.y * 32;
    const unsigned short* I = in + (size_t)b * 1024 * 1024;
    unsigned short* O = out + (size_t)b * 1024 * 1024;
    const int x = threadIdx.x, y0 = threadIdx.y;
#pragma unroll
    for (int yy = y0; yy < 32; yy += 8) tile[yy][x] = I[(size_t)(s0 + yy) * 1024 + d0 + x];
    __syncthreads();
#pragma unroll
    for (int yy = y0; yy < 32; yy += 8) O[(size_t)(d0 + yy) * 1024 + s0 + x] = tile[x][yy];
}

// ---------------- GEMM v2 (unchanged): global_load_lds, BK=64, XOR swizzle ----------------
template <int BM, int BN, bool RELU, bool RES, bool OUT_BF16>
__global__ __launch_bounds__(256) void gemm2(const unsigned short* __restrict__ A,
                                             const unsigned short* __restrict__ Bt,
                                             const float* __restrict__ bias,
                                             const float* __restrict__ res,
                                             void* __restrict__ C_v,
                                             int M, int N, int K) {
    constexpr int WM = BM / 2, WN = BN / 2;
    constexpr int FM = WM / 16, FN = WN / 16;
    __shared__ __align__(16) unsigned short As[BM * 64];
    __shared__ __align__(16) unsigned short Bs[BN * 64];

    const int t = threadIdx.x;
    const int lane = t & 63, w = t >> 6;
    const int wr = w >> 1, wc = w & 1;
    const int lr = lane & 15, g = lane >> 4;

    const int nwg = gridDim.x;
    const int cpx = nwg >> 3;
    const int wg = blockIdx.x;
    const int swz = (wg & 7) * cpx + (wg >> 3);
    const int NB = N / BN;
    const int m0 = (swz / NB) * BM, n0 = (swz % NB) * BN;

    f32x4 acc[FM][FN];
#pragma unroll
    for (int i = 0; i < FM; ++i)
#pragma unroll
        for (int j = 0; j < FN; ++j) acc[i][j] = (f32x4)0.0f;

    for (int k0 = 0; k0 < K; k0 += 64) {
        __syncthreads();
#pragma unroll
        for (int i = 0; i < BM / 32; ++i) {
            int id = i * 256 + t;
            int row = id >> 3, ch = id & 7;
            gld_lds16(&A[(size_t)(m0 + row) * K + k0 + ((ch ^ (row & 7)) * 8)],
                      &As[(size_t)(i * 256 + (t & ~63)) * 8]);
        }
#pragma unroll
        for (int i = 0; i < BN / 32; ++i) {
            int id = i * 256 + t;
            int row = id >> 3, ch = id & 7;
            gld_lds16(&Bt[(size_t)(n0 + row) * K + k0 + ((ch ^ (row & 7)) * 8)],
                      &Bs[(size_t)(i * 256 + (t & ~63)) * 8]);
        }
        __syncthreads();

        short8 af[FM][2], bfr[FN][2];
#pragma unroll
        for (int mi = 0; mi < FM; ++mi) {
            int row = wr * WM + mi * 16 + lr;
#pragma unroll
            for (int ks = 0; ks < 2; ++ks) {
                int ch = (ks * 4 + g) ^ (row & 7);
                af[mi][ks] = *(const short8*)&As[row * 64 + ch * 8];
            }
        }
#pragma unroll
        for (int ni = 0; ni < FN; ++ni) {
            int row = wc * WN + ni * 16 + lr;
#pragma unroll
            for (int ks = 0; ks < 2; ++ks) {
                int ch = (ks * 4 + g) ^ (row & 7);
                bfr[ni][ks] = *(const short8*)&Bs[row * 64 + ch * 8];
            }
        }
#pragma unroll
        for (int ks = 0; ks < 2; ++ks)
#pragma unroll
            for (int mi = 0; mi < FM; ++mi)
#pragma unroll
                for (int ni = 0; ni < FN; ++ni)
                    acc[mi][ni] = __builtin_amdgcn_mfma_f32_16x16x32_bf16(af[mi][ks], bfr[ni][ks], acc[mi][ni], 0, 0, 0);
    }

    const int lg = g;
#pragma unroll
    for (int ni = 0; ni < FN; ++ni) {
        int col = n0 + wc * WN + ni * 16 + lr;
        float bv = bias[col];
#pragma unroll
        for (int mi = 0; mi < FM; ++mi) {
            int row0 = m0 + wr * WM + mi * 16 + lg * 4;
#pragma unroll
            for (int i = 0; i < 4; ++i) {
                int row = row0 + i;
                float x = acc[mi][ni][i] + bv;
                if (RES) x += res[(size_t)row * N + col];
                if (RELU) x = fmaxf(x, 0.0f);
                if (OUT_BF16)
                    ((unsigned short*)C_v)[(size_t)row * N + col] = f2b(x);
                else
                    ((float*)C_v)[(size_t)row * N + col] = x;
            }
        }
    }
}

// ---------------- GEMM v3: 256x256 tile, BK=32, 4-deep ring, counted vmcnt + raw barrier ----
// 512 threads = 8 waves (2M x 4N); per-wave output 128x64 (8x4 frags). Per K-tile:
// issue tile t+2's 4 gld_lds -> 12 ds_read_b128 -> 32 MFMA -> vmcnt(4) (t+1's loads done,
// per-wave) -> s_barrier (raw; no drain). Buffer t+2 last read at t-2 (2 barriers ago).
// LDS chunk swizzle ch^((row>>1)&3): 2 lanes/bank-slot on ds_read = free.
template <bool RELU, bool OUT_BF16>
__global__ __launch_bounds__(512, 2) void gemm3(const unsigned short* __restrict__ A,
                                                const unsigned short* __restrict__ Bt,
                                                const float* __restrict__ bias,
                                                void* __restrict__ C_v,
                                                int M, int N, int K) {
    __shared__ __align__(16) unsigned short As[4][256 * 32];
    __shared__ __align__(16) unsigned short Bs[4][256 * 32];

    const int t = threadIdx.x;
    const int lane = t & 63;
    const int wid = t >> 6;
    const int wr = wid >> 2, wc = wid & 3;
    const int lr = lane & 15, g = lane >> 4;

    const int nwg = gridDim.x;
    const int cpx = nwg >> 3;
    const int wg = blockIdx.x;
    const int swz = (wg & 7) * cpx + (wg >> 3);
    const int NB = N / 256;
    const int m0 = (swz / NB) * 256, n0 = (swz % NB) * 256;

    f32x4 acc[8][4];
#pragma unroll
    for (int i = 0; i < 8; ++i)
#pragma unroll
        for (int j = 0; j < 4; ++j) acc[i][j] = (f32x4)0.0f;

    const int NT = K / 32;

    // staging: 2 sweeps x 512 thr; id=s*512+t -> row=id>>2 (0..255), ch=id&3; LDS linear dest.
#define STAGE3(kt)                                                                          \
    {                                                                                       \
        const int buf_ = (kt) & 3;                                                          \
        const int k0_ = (kt) * 32;                                                          \
        _Pragma("unroll") for (int s = 0; s < 2; ++s) {                                     \
            int id = s * 512 + t;                                                           \
            int row = id >> 2;                                                              \
            int ch = (id & 3) ^ ((row >> 1) & 3);                                           \
            gld_lds16(&A[(size_t)(m0 + row) * K + k0_ + ch * 8],                            \
                      &As[buf_][(size_t)(s * 512 + (t & ~63)) * 8]);                        \
            gld_lds16(&Bt[(size_t)(n0 + row) * K + k0_ + ch * 8],                           \
                      &Bs[buf_][(size_t)(s * 512 + (t & ~63)) * 8]);                        \
        }                                                                                   \
    }

    STAGE3(0);
    STAGE3(1);
    asm volatile("s_waitcnt vmcnt(4)" ::: "memory");  // tile 0 resident (per-wave)
    __builtin_amdgcn_sched_barrier(0);
    __builtin_amdgcn_s_barrier();

    for (int kt = 0; kt < NT; ++kt) {
        const int buf = kt & 3;
        if (kt + 2 < NT) STAGE3(kt + 2);

        short8 af[8], bf[4];
#pragma unroll
        for (int mi = 0; mi < 8; ++mi) {
            int row = wr * 128 + mi * 16 + lr;
            int ch = g ^ ((row >> 1) & 3);
            af[mi] = *(const short8*)&As[buf][row * 32 + ch * 8];
        }
#pragma unroll
        for (int nj = 0; nj < 4; ++nj) {
            int row = wc * 64 + nj * 16 + lr;
            int ch = g ^ ((row >> 1) & 3);
            bf[nj] = *(const short8*)&Bs[buf][row * 32 + ch * 8];
        }

        __builtin_amdgcn_s_setprio(1);
#pragma unroll
        for (int mi = 0; mi < 8; ++mi)
#pragma unroll
            for (int nj = 0; nj < 4; ++nj)
                acc[mi][nj] = __builtin_amdgcn_mfma_f32_16x16x32_bf16(af[mi], bf[nj], acc[mi][nj], 0, 0, 0);
        __builtin_amdgcn_s_setprio(0);

        if (kt + 2 < NT) {
            asm volatile("s_waitcnt vmcnt(4)" ::: "memory");  // tile kt+1 resident
        } else if (kt + 1 < NT) {
            asm volatile("s_waitcnt vmcnt(0)" ::: "memory");  // last prefetch drained
        }
        __builtin_amdgcn_sched_barrier(0);
        __builtin_amdgcn_s_barrier();
    }
#undef STAGE3

    // epilogue: C row = m0 + wr*128 + mi*16 + g*4 + i, col = n0 + wc*64 + nj*16 + lr
#pragma unroll
    for (int nj = 0; nj < 4; ++nj) {
        int col = n0 + wc * 64 + nj * 16 + lr;
        float bv = bias[col];
#pragma unroll
        for (int mi = 0; mi < 8; ++mi) {
            int row0 = m0 + wr * 128 + mi * 16 + g * 4;
#pragma unroll
            for (int i = 0; i < 4; ++i) {
                int row = row0 + i;
                float x = acc[mi][nj][i] + bv;
                if (RELU) x = fmaxf(x, 0.0f);
                if (OUT_BF16)
                    ((unsigned short*)C_v)[(size_t)row * N + col] = f2b(x);
                else
                    ((float*)C_v)[(size_t)row * N + col] = x;
            }
        }
    }
}

// ---------------- MFMA flash attention (r4 structure, bh-major grid) ----------
__global__ __launch_bounds__(256) void attn_mfma_kernel(const unsigned short* __restrict__ p,
                                                        const unsigned short* __restrict__ pT,
                                                        unsigned short* __restrict__ out) {
    __shared__ __align__(16) unsigned short Ks[64 * 64];
    __shared__ __align__(16) unsigned short Vt[64 * 64];
    __shared__ __align__(16) unsigned short Ps[4 * 16 * 64];

    const int t = threadIdx.x;
    const int lane = t & 63, w = t >> 6;
    const int lr = lane & 15, g = lane >> 4;
    const int bh = blockIdx.x;
    const int qblk = blockIdx.y;
    const int b = bh >> 4, h = bh & 15;

    const unsigned short* Pm = p + (size_t)b * (1024 * 1024) + h * 64;
    const unsigned short* PT = pT + (size_t)b * (1024 * 1024) + (size_t)(h * 64) * 1024;

    const int q0 = qblk * 64 + w * 16;
    short8 qa0 = *(const short8*)&Pm[(size_t)(q0 + lr) * 1024 + g * 8];
    short8 qa1 = *(const short8*)&Pm[(size_t)(q0 + lr) * 1024 + 32 + g * 8];

    f32x4 acc[4];
#pragma unroll
    for (int i = 0; i < 4; ++i) acc[i] = (f32x4)0.0f;
    float mrow[4] = {-1e30f, -1e30f, -1e30f, -1e30f};
    float lsum[4] = {0.f, 0.f, 0.f, 0.f};

    unsigned short* Pw = &Ps[w * 16 * 64];

    for (int kt = 0; kt < 16; ++kt) {
        const int key0 = kt * 64;
        __syncthreads();
#pragma unroll
        for (int i = 0; i < 2; ++i) {
            int id = t + i * 256;
            int row = id >> 3, ch = (id & 7) * 8;
            int sw = ch ^ ((row & 7) << 3);
            short8 kv = *(const short8*)&Pm[(size_t)(key0 + row) * 1024 + ch];
            *(short8*)&Ks[row * 64 + sw] = kv;
            short8 vv = *(const short8*)&PT[(size_t)row * 1024 + key0 + ch];
            *(short8*)&Vt[row * 64 + sw] = vv;
        }
        __syncthreads();

        f32x4 s_acc[4];
#pragma unroll
        for (int kg = 0; kg < 4; ++kg) {
            s_acc[kg] = (f32x4)0.0f;
            int krow = kg * 16 + lr;
            int swz = (krow & 7) << 3;
            short8 kb0 = *(const short8*)&Ks[krow * 64 + ((g * 8) ^ swz)];
            short8 kb1 = *(const short8*)&Ks[krow * 64 + ((32 + g * 8) ^ swz)];
            s_acc[kg] = __builtin_amdgcn_mfma_f32_16x16x32_bf16(qa0, kb0, s_acc[kg], 0, 0, 0);
            s_acc[kg] = __builtin_amdgcn_mfma_f32_16x16x32_bf16(qa1, kb1, s_acc[kg], 0, 0, 0);
        }

#pragma unroll
        for (int reg = 0; reg < 4; ++reg) {
            float mx = fmaxf(fmaxf(s_acc[0][reg], s_acc[1][reg]),
                             fmaxf(s_acc[2][reg], s_acc[3][reg])) * 0.125f;
            mx = fmaxf(mx, __shfl_xor(mx, 1));
            mx = fmaxf(mx, __shfl_xor(mx, 2));
            mx = fmaxf(mx, __shfl_xor(mx, 4));
            mx = fmaxf(mx, __shfl_xor(mx, 8));
            float mnew = fmaxf(mrow[reg], mx);
            float scale = __expf(mrow[reg] - mnew);
            mrow[reg] = mnew;
            float psum = 0.f;
#pragma unroll
            for (int kg = 0; kg < 4; ++kg) {
                float pv = __expf(s_acc[kg][reg] * 0.125f - mnew);
                s_acc[kg][reg] = pv;
                psum += pv;
            }
            psum += __shfl_xor(psum, 1);
            psum += __shfl_xor(psum, 2);
            psum += __shfl_xor(psum, 4);
            psum += __shfl_xor(psum, 8);
            lsum[reg] = lsum[reg] * scale + psum;
#pragma unroll
            for (int dg = 0; dg < 4; ++dg) acc[dg][reg] *= scale;
        }

#pragma unroll
        for (int reg = 0; reg < 4; ++reg) {
            int q = g * 4 + reg;
            int swz = (q & 7) << 3;
#pragma unroll
            for (int kg = 0; kg < 4; ++kg) {
                int key = lr + 16 * kg;
                Pw[q * 64 + (key ^ swz)] = f2b(s_acc[kg][reg]);
            }
        }
        int pswz = (lr & 7) << 3;
        short8 pa0 = *(const short8*)&Pw[lr * 64 + ((g * 8) ^ pswz)];
        short8 pa1 = *(const short8*)&Pw[lr * 64 + ((32 + g * 8) ^ pswz)];

#pragma unroll
        for (int dg = 0; dg < 4; ++dg) {
            int drow = dg * 16 + lr;
            int swz = (drow & 7) << 3;
            short8 vb0 = *(const short8*)&Vt[drow * 64 + ((g * 8) ^ swz)];
            short8 vb1 = *(const short8*)&Vt[drow * 64 + ((32 + g * 8) ^ swz)];
            acc[dg] = __builtin_amdgcn_mfma_f32_16x16x32_bf16(pa0, vb0, acc[dg], 0, 0, 0);
            acc[dg] = __builtin_amdgcn_mfma_f32_16x16x32_bf16(pa1, vb1, acc[dg], 0, 0, 0);
        }
    }

    unsigned short* O = out + (size_t)b * (1024 * 1024) + h * 64;
#pragma unroll
    for (int reg = 0; reg < 4; ++reg) {
        float inv = 1.0f / lsum[reg];
        int q = q0 + g * 4 + reg;
#pragma unroll
        for (int dg = 0; dg < 4; ++dg) {
            O[(size_t)q * 1024 + dg * 16 + lr] = f2b(acc[dg][reg] * inv);
        }
    }
}

// ---------------- launch ----------------
extern "C" void kernel_launch(void* const* d_in, const int* in_sizes, int n_in,
                              void* d_out, int out_size, void* d_ws, size_t ws_size,
                              hipStream_t stream) {
    const float* x = (const float*)d_in[0];
    const float* wq_w = (const float*)d_in[1];
    const float* wq_b = (const float*)d_in[2];
    const float* wo_w = (const float*)d_in[3];
    const float* wo_b = (const float*)d_in[4];
    const float* ff1_w = (const float*)d_in[5];
    const float* ff1_b = (const float*)d_in[6];
    const float* ff2_w = (const float*)d_in[7];
    const float* ff2_b = (const float*)d_in[8];
    const float* alpha1 = (const float*)d_in[9];
    const float* bias1 = (const float*)d_in[10];
    const float* alpha2 = (const float*)d_in[11];
    const float* bias2 = (const float*)d_in[12];
    const float* alpha3 = (const float*)d_in[13];
    const float* bias3 = (const float*)d_in[14];
    float* out = (float*)d_out;

    const size_t MB = 1u << 20;
    char* ws = (char*)d_ws;
    unsigned short* wq_t = (unsigned short*)(ws + 0 * MB);
    unsigned short* wo_t = (unsigned short*)(ws + 2 * MB);
    unsigned short* ff1_t = (unsigned short*)(ws + 4 * MB);
    unsigned short* ff2_t = (unsigned short*)(ws + 12 * MB);
    unsigned short* lnbuf = (unsigned short*)(ws + 20 * MB);
    unsigned short* pbuf = (unsigned short*)(ws + 28 * MB);
    unsigned short* attn = (unsigned short*)(ws + 36 * MB);
    float* h1 = (float*)(ws + 44 * MB);
    unsigned short* pbT = (unsigned short*)(ws + 60 * MB);
    unsigned short* mid = (unsigned short*)(ws + 60 * MB);
    float* h2 = (float*)(ws + 28 * MB);

    const int M = 4096;

    transpose_cast_kernel<<<dim3(32, 32), dim3(32, 8), 0, stream>>>(wq_w, wq_t, 1024, 1024);
    transpose_cast_kernel<<<dim3(32, 32), dim3(32, 8), 0, stream>>>(wo_w, wo_t, 1024, 1024);
    transpose_cast_kernel<<<dim3(128, 32), dim3(32, 8), 0, stream>>>(ff1_w, ff1_t, 1024, 4096);
    transpose_cast_kernel<<<dim3(32, 128), dim3(32, 8), 0, stream>>>(ff2_w, ff2_t, 4096, 1024);

    ln_kernel<true><<<M, 256, 0, stream>>>(x, lnbuf, alpha1, bias1);
    gemm2<128, 64, false, false, true><<<512, 256, 0, stream>>>(lnbuf, wq_t, wq_b, nullptr, pbuf, M, 1024, 1024);
    transpose_bf16_batch<<<dim3(32, 32, 4), dim3(32, 8), 0, stream>>>(pbuf, pbT);
    attn_mfma_kernel<<<dim3(64, 16), 256, 0, stream>>>(pbuf, pbT, attn);
    gemm2<128, 64, false, true, false><<<512, 256, 0, stream>>>(attn, wo_t, wo_b, x, h1, M, 1024, 1024);
    ln_kernel<true><<<M, 256, 0, stream>>>(h1, lnbuf, alpha2, bias2);
    // mid = relu(ln2 @ ff1 + ff1_b): 256x256 pipelined kernel, 256 blocks (1/CU)
    gemm3<true, true><<<256, 512, 0, stream>>>(lnbuf, ff1_t, ff1_b, mid, M, 4096, 1024);
    gemm2<128, 64, false, true, false><<<512, 256, 0, stream>>>(mid, ff2_t, ff2_b, h1, h2, M, 1024, 4096);
    ln_kernel<false><<<M, 256, 0, stream>>>(h2, out, alpha3, bias3);
}

// Round 12
// 251.245 us; speedup vs baseline: 1.0592x; 1.0130x over previous
//
#include <hip/hip_runtime.h>

typedef short short8 __attribute__((ext_vector_type(8)));
typedef float f32x4 __attribute__((ext_vector_type(4)));
typedef unsigned short u16x4 __attribute__((ext_vector_type(4)));

#define DEV static __device__ __forceinline__

DEV float b2f(unsigned short u) { return __uint_as_float(((unsigned)u) << 16); }
DEV unsigned short f2b(float f) {
    unsigned u = __float_as_uint(f);
    u += 0x7FFFu + ((u >> 16) & 1u);
    return (unsigned short)(u >> 16);
}
DEV float wred_sum(float v) {
#pragma unroll
    for (int o = 32; o; o >>= 1) v += __shfl_xor(v, o);
    return v;
}

DEV void gld_lds16(const unsigned short* g, unsigned short* l) {
    __builtin_amdgcn_global_load_lds((const __attribute__((address_space(1))) void*)g,
                                     (__attribute__((address_space(3))) void*)l, 16, 0, 0);
}

// ---------------- LayerNorm ----------------
template <bool OUT_BF16>
__global__ __launch_bounds__(256) void ln_kernel(const float* __restrict__ in,
                                                 void* __restrict__ out_v,
                                                 const float* __restrict__ alpha_p,
                                                 const float* __restrict__ bias_p) {
    __shared__ float redA[4], redB[4];
    const int row = blockIdx.x;
    const int t = threadIdx.x;
    const int lane = t & 63, w = t >> 6;

    f32x4 xv = *(const f32x4*)&in[(size_t)row * 1024 + t * 4];

    float s = wred_sum(xv[0] + xv[1] + xv[2] + xv[3]);
    if (lane == 0) redA[w] = s;
    __syncthreads();
    float mean = (redA[0] + redA[1] + redA[2] + redA[3]) * (1.0f / 1024.0f);

    float d0 = xv[0] - mean, d1 = xv[1] - mean, d2 = xv[2] - mean, d3 = xv[3] - mean;
    float ss = wred_sum(d0 * d0 + d1 * d1 + d2 * d2 + d3 * d3);
    if (lane == 0) redB[w] = ss;
    __syncthreads();
    float var = (redB[0] + redB[1] + redB[2] + redB[3]) * (1.0f / 1023.0f);
    float denom = sqrtf(var) + 1e-9f;
    float inv = alpha_p[0] / denom;
    float bias = bias_p[0];

    if (OUT_BF16) {
        u16x4 o;
        o[0] = f2b(d0 * inv + bias);
        o[1] = f2b(d1 * inv + bias);
        o[2] = f2b(d2 * inv + bias);
        o[3] = f2b(d3 * inv + bias);
        *(u16x4*)&((unsigned short*)out_v)[(size_t)row * 1024 + t * 4] = o;
    } else {
        f32x4 o;
        o[0] = d0 * inv + bias;
        o[1] = d1 * inv + bias;
        o[2] = d2 * inv + bias;
        o[3] = d3 * inv + bias;
        *(f32x4*)&((float*)out_v)[(size_t)row * 1024 + t * 4] = o;
    }
}

// ---------------- f32 -> bf16 transpose ----------------
__global__ __launch_bounds__(256) void transpose_cast_kernel(const float* __restrict__ in,
                                                             unsigned short* __restrict__ out,
                                                             int R, int C) {
    __shared__ unsigned short tile[32][33];
    const int c0 = blockIdx.x * 32, r0 = blockIdx.y * 32;
    const int x = threadIdx.x, y0 = threadIdx.y;
#pragma unroll
    for (int yy = y0; yy < 32; yy += 8) tile[yy][x] = f2b(in[(size_t)(r0 + yy) * C + c0 + x]);
    __syncthreads();
#pragma unroll
    for (int yy = y0; yy < 32; yy += 8) out[(size_t)(c0 + yy) * R + r0 + x] = tile[x][yy];
}

// ---------------- bf16 [b][s][d] -> [b][d][s] transpose ----------------
__global__ __launch_bounds__(256) void transpose_bf16_batch(const unsigned short* __restrict__ in,
                                                            unsigned short* __restrict__ out) {
    __shared__ unsigned short tile[32][33];
    const int b = blockIdx.z;
    const int d0 = blockIdx.x * 32, s0 = blockIdx.y * 32;
    const unsigned short* I = in + (size_t)b * 1024 * 1024;
    unsigned short* O = out + (size_t)b * 1024 * 1024;
    const int x = threadIdx.x, y0 = threadIdx.y;
#pragma unroll
    for (int yy = y0; yy < 32; yy += 8) tile[yy][x] = I[(size_t)(s0 + yy) * 1024 + d0 + x];
    __syncthreads();
#pragma unroll
    for (int yy = y0; yy < 32; yy += 8) O[(size_t)(d0 + yy) * 1024 + s0 + x] = tile[x][yy];
}

// ---------------- GEMM v2b: 128x64(/128) tile, BK=64, RING-3 + counted vmcnt + raw barrier ----
// Same tile/swizzle/epilogue as gemm2, but 3-buffer LDS ring: per K-tile issue tile t+2's
// 6 gld_lds (4 A + 2 B per wave), ds_read+16 MFMA on tile t, vmcnt(6) (tile t+1 resident),
// raw s_barrier (no drain). Buffer (t+2)%3 was read at t-1, completed pre-barrier. [T3/T4]
template <int BM, int BN, bool RELU, bool RES, bool OUT_BF16>
__global__ __launch_bounds__(256) void gemm2b(const unsigned short* __restrict__ A,
                                              const unsigned short* __restrict__ Bt,
                                              const float* __restrict__ bias,
                                              const float* __restrict__ res,
                                              void* __restrict__ C_v,
                                              int M, int N, int K) {
    constexpr int WM = BM / 2, WN = BN / 2;
    constexpr int FM = WM / 16, FN = WN / 16;
    __shared__ __align__(16) unsigned short As[3][BM * 64];
    __shared__ __align__(16) unsigned short Bs[3][BN * 64];

    const int t = threadIdx.x;
    const int lane = t & 63, w = t >> 6;
    const int wr = w >> 1, wc = w & 1;
    const int lr = lane & 15, g = lane >> 4;

    const int nwg = gridDim.x;
    const int cpx = nwg >> 3;
    const int wg = blockIdx.x;
    const int swz = (wg & 7) * cpx + (wg >> 3);
    const int NB = N / BN;
    const int m0 = (swz / NB) * BM, n0 = (swz % NB) * BN;

    f32x4 acc[FM][FN];
#pragma unroll
    for (int i = 0; i < FM; ++i)
#pragma unroll
        for (int j = 0; j < FN; ++j) acc[i][j] = (f32x4)0.0f;

    const int NT = K / 64;

#define STAGE2B(kt)                                                                        \
    {                                                                                      \
        const int buf_ = (kt) % 3;                                                         \
        const int k0_ = (kt) * 64;                                                         \
        _Pragma("unroll") for (int i = 0; i < BM / 32; ++i) {                              \
            int id = i * 256 + t;                                                          \
            int row = id >> 3, ch = (id & 7) ^ (row & 7);                                  \
            gld_lds16(&A[(size_t)(m0 + row) * K + k0_ + ch * 8],                           \
                      &As[buf_][(size_t)(i * 256 + (t & ~63)) * 8]);                       \
        }                                                                                  \
        _Pragma("unroll") for (int i = 0; i < BN / 32; ++i) {                              \
            int id = i * 256 + t;                                                          \
            int row = id >> 3, ch = (id & 7) ^ (row & 7);                                  \
            gld_lds16(&Bt[(size_t)(n0 + row) * K + k0_ + ch * 8],                          \
                      &Bs[buf_][(size_t)(i * 256 + (t & ~63)) * 8]);                       \
        }                                                                                  \
    }

    STAGE2B(0);
    STAGE2B(1);
    asm volatile("s_waitcnt vmcnt(6)" ::: "memory");  // tile 0's 6 per-wave loads done
    __builtin_amdgcn_sched_barrier(0);
    __builtin_amdgcn_s_barrier();

    for (int kt = 0; kt < NT; ++kt) {
        const int buf = kt % 3;
        if (kt + 2 < NT) STAGE2B(kt + 2);

        short8 af[FM][2], bfr[FN][2];
#pragma unroll
        for (int mi = 0; mi < FM; ++mi) {
            int row = wr * WM + mi * 16 + lr;
#pragma unroll
            for (int ks = 0; ks < 2; ++ks) {
                int ch = (ks * 4 + g) ^ (row & 7);
                af[mi][ks] = *(const short8*)&As[buf][row * 64 + ch * 8];
            }
        }
#pragma unroll
        for (int ni = 0; ni < FN; ++ni) {
            int row = wc * WN + ni * 16 + lr;
#pragma unroll
            for (int ks = 0; ks < 2; ++ks) {
                int ch = (ks * 4 + g) ^ (row & 7);
                bfr[ni][ks] = *(const short8*)&Bs[buf][row * 64 + ch * 8];
            }
        }

        __builtin_amdgcn_s_setprio(1);
#pragma unroll
        for (int ks = 0; ks < 2; ++ks)
#pragma unroll
            for (int mi = 0; mi < FM; ++mi)
#pragma unroll
                for (int ni = 0; ni < FN; ++ni)
                    acc[mi][ni] = __builtin_amdgcn_mfma_f32_16x16x32_bf16(af[mi][ks], bfr[ni][ks], acc[mi][ni], 0, 0, 0);
        __builtin_amdgcn_s_setprio(0);

        if (kt + 2 < NT) {
            asm volatile("s_waitcnt vmcnt(6)" ::: "memory");  // tile kt+1 resident
        } else if (kt + 1 < NT) {
            asm volatile("s_waitcnt vmcnt(0)" ::: "memory");  // last prefetch drained
        }
        __builtin_amdgcn_sched_barrier(0);
        __builtin_amdgcn_s_barrier();
    }
#undef STAGE2B

    const int lg = g;
#pragma unroll
    for (int ni = 0; ni < FN; ++ni) {
        int col = n0 + wc * WN + ni * 16 + lr;
        float bv = bias[col];
#pragma unroll
        for (int mi = 0; mi < FM; ++mi) {
            int row0 = m0 + wr * WM + mi * 16 + lg * 4;
#pragma unroll
            for (int i = 0; i < 4; ++i) {
                int row = row0 + i;
                float x = acc[mi][ni][i] + bv;
                if (RES) x += res[(size_t)row * N + col];
                if (RELU) x = fmaxf(x, 0.0f);
                if (OUT_BF16)
                    ((unsigned short*)C_v)[(size_t)row * N + col] = f2b(x);
                else
                    ((float*)C_v)[(size_t)row * N + col] = x;
            }
        }
    }
}

// ---------------- GEMM v3: 256x256 tile, BK=32, 4-deep ring (FFN1) ----------------
template <bool RELU, bool OUT_BF16>
__global__ __launch_bounds__(512, 2) void gemm3(const unsigned short* __restrict__ A,
                                                const unsigned short* __restrict__ Bt,
                                                const float* __restrict__ bias,
                                                void* __restrict__ C_v,
                                                int M, int N, int K) {
    __shared__ __align__(16) unsigned short As[4][256 * 32];
    __shared__ __align__(16) unsigned short Bs[4][256 * 32];

    const int t = threadIdx.x;
    const int lane = t & 63;
    const int wid = t >> 6;
    const int wr = wid >> 2, wc = wid & 3;
    const int lr = lane & 15, g = lane >> 4;

    const int nwg = gridDim.x;
    const int cpx = nwg >> 3;
    const int wg = blockIdx.x;
    const int swz = (wg & 7) * cpx + (wg >> 3);
    const int NB = N / 256;
    const int m0 = (swz / NB) * 256, n0 = (swz % NB) * 256;

    f32x4 acc[8][4];
#pragma unroll
    for (int i = 0; i < 8; ++i)
#pragma unroll
        for (int j = 0; j < 4; ++j) acc[i][j] = (f32x4)0.0f;

    const int NT = K / 32;

#define STAGE3(kt)                                                                          \
    {                                                                                       \
        const int buf_ = (kt) & 3;                                                          \
        const int k0_ = (kt) * 32;                                                          \
        _Pragma("unroll") for (int s = 0; s < 2; ++s) {                                     \
            int id = s * 512 + t;                                                           \
            int row = id >> 2;                                                              \
            int ch = (id & 3) ^ ((row >> 1) & 3);                                           \
            gld_lds16(&A[(size_t)(m0 + row) * K + k0_ + ch * 8],                            \
                      &As[buf_][(size_t)(s * 512 + (t & ~63)) * 8]);                        \
            gld_lds16(&Bt[(size_t)(n0 + row) * K + k0_ + ch * 8],                           \
                      &Bs[buf_][(size_t)(s * 512 + (t & ~63)) * 8]);                        \
        }                                                                                   \
    }

    STAGE3(0);
    STAGE3(1);
    asm volatile("s_waitcnt vmcnt(4)" ::: "memory");
    __builtin_amdgcn_sched_barrier(0);
    __builtin_amdgcn_s_barrier();

    for (int kt = 0; kt < NT; ++kt) {
        const int buf = kt & 3;
        if (kt + 2 < NT) STAGE3(kt + 2);

        short8 af[8], bf[4];
#pragma unroll
        for (int mi = 0; mi < 8; ++mi) {
            int row = wr * 128 + mi * 16 + lr;
            int ch = g ^ ((row >> 1) & 3);
            af[mi] = *(const short8*)&As[buf][row * 32 + ch * 8];
        }
#pragma unroll
        for (int nj = 0; nj < 4; ++nj) {
            int row = wc * 64 + nj * 16 + lr;
            int ch = g ^ ((row >> 1) & 3);
            bf[nj] = *(const short8*)&Bs[buf][row * 32 + ch * 8];
        }

        __builtin_amdgcn_s_setprio(1);
#pragma unroll
        for (int mi = 0; mi < 8; ++mi)
#pragma unroll
            for (int nj = 0; nj < 4; ++nj)
                acc[mi][nj] = __builtin_amdgcn_mfma_f32_16x16x32_bf16(af[mi], bf[nj], acc[mi][nj], 0, 0, 0);
        __builtin_amdgcn_s_setprio(0);

        if (kt + 2 < NT) {
            asm volatile("s_waitcnt vmcnt(4)" ::: "memory");
        } else if (kt + 1 < NT) {
            asm volatile("s_waitcnt vmcnt(0)" ::: "memory");
        }
        __builtin_amdgcn_sched_barrier(0);
        __builtin_amdgcn_s_barrier();
    }
#undef STAGE3

#pragma unroll
    for (int nj = 0; nj < 4; ++nj) {
        int col = n0 + wc * 64 + nj * 16 + lr;
        float bv = bias[col];
#pragma unroll
        for (int mi = 0; mi < 8; ++mi) {
            int row0 = m0 + wr * 128 + mi * 16 + g * 4;
#pragma unroll
            for (int i = 0; i < 4; ++i) {
                int row = row0 + i;
                float x = acc[mi][nj][i] + bv;
                if (RELU) x = fmaxf(x, 0.0f);
                if (OUT_BF16)
                    ((unsigned short*)C_v)[(size_t)row * N + col] = f2b(x);
                else
                    ((float*)C_v)[(size_t)row * N + col] = x;
            }
        }
    }
}

// ---------------- MFMA flash attention (r4 structure, bh-major grid) ----------
__global__ __launch_bounds__(256) void attn_mfma_kernel(const unsigned short* __restrict__ p,
                                                        const unsigned short* __restrict__ pT,
                                                        unsigned short* __restrict__ out) {
    __shared__ __align__(16) unsigned short Ks[64 * 64];
    __shared__ __align__(16) unsigned short Vt[64 * 64];
    __shared__ __align__(16) unsigned short Ps[4 * 16 * 64];

    const int t = threadIdx.x;
    const int lane = t & 63, w = t >> 6;
    const int lr = lane & 15, g = lane >> 4;
    const int bh = blockIdx.x;
    const int qblk = blockIdx.y;
    const int b = bh >> 4, h = bh & 15;

    const unsigned short* Pm = p + (size_t)b * (1024 * 1024) + h * 64;
    const unsigned short* PT = pT + (size_t)b * (1024 * 1024) + (size_t)(h * 64) * 1024;

    const int q0 = qblk * 64 + w * 16;
    short8 qa0 = *(const short8*)&Pm[(size_t)(q0 + lr) * 1024 + g * 8];
    short8 qa1 = *(const short8*)&Pm[(size_t)(q0 + lr) * 1024 + 32 + g * 8];

    f32x4 acc[4];
#pragma unroll
    for (int i = 0; i < 4; ++i) acc[i] = (f32x4)0.0f;
    float mrow[4] = {-1e30f, -1e30f, -1e30f, -1e30f};
    float lsum[4] = {0.f, 0.f, 0.f, 0.f};

    unsigned short* Pw = &Ps[w * 16 * 64];

    for (int kt = 0; kt < 16; ++kt) {
        const int key0 = kt * 64;
        __syncthreads();
#pragma unroll
        for (int i = 0; i < 2; ++i) {
            int id = t + i * 256;
            int row = id >> 3, ch = (id & 7) * 8;
            int sw = ch ^ ((row & 7) << 3);
            short8 kv = *(const short8*)&Pm[(size_t)(key0 + row) * 1024 + ch];
            *(short8*)&Ks[row * 64 + sw] = kv;
            short8 vv = *(const short8*)&PT[(size_t)row * 1024 + key0 + ch];
            *(short8*)&Vt[row * 64 + sw] = vv;
        }
        __syncthreads();

        f32x4 s_acc[4];
#pragma unroll
        for (int kg = 0; kg < 4; ++kg) {
            s_acc[kg] = (f32x4)0.0f;
            int krow = kg * 16 + lr;
            int swz = (krow & 7) << 3;
            short8 kb0 = *(const short8*)&Ks[krow * 64 + ((g * 8) ^ swz)];
            short8 kb1 = *(const short8*)&Ks[krow * 64 + ((32 + g * 8) ^ swz)];
            s_acc[kg] = __builtin_amdgcn_mfma_f32_16x16x32_bf16(qa0, kb0, s_acc[kg], 0, 0, 0);
            s_acc[kg] = __builtin_amdgcn_mfma_f32_16x16x32_bf16(qa1, kb1, s_acc[kg], 0, 0, 0);
        }

#pragma unroll
        for (int reg = 0; reg < 4; ++reg) {
            float mx = fmaxf(fmaxf(s_acc[0][reg], s_acc[1][reg]),
                             fmaxf(s_acc[2][reg], s_acc[3][reg])) * 0.125f;
            mx = fmaxf(mx, __shfl_xor(mx, 1));
            mx = fmaxf(mx, __shfl_xor(mx, 2));
            mx = fmaxf(mx, __shfl_xor(mx, 4));
            mx = fmaxf(mx, __shfl_xor(mx, 8));
            float mnew = fmaxf(mrow[reg], mx);
            float scale = __expf(mrow[reg] - mnew);
            mrow[reg] = mnew;
            float psum = 0.f;
#pragma unroll
            for (int kg = 0; kg < 4; ++kg) {
                float pv = __expf(s_acc[kg][reg] * 0.125f - mnew);
                s_acc[kg][reg] = pv;
                psum += pv;
            }
            psum += __shfl_xor(psum, 1);
            psum += __shfl_xor(psum, 2);
            psum += __shfl_xor(psum, 4);
            psum += __shfl_xor(psum, 8);
            lsum[reg] = lsum[reg] * scale + psum;
#pragma unroll
            for (int dg = 0; dg < 4; ++dg) acc[dg][reg] *= scale;
        }

#pragma unroll
        for (int reg = 0; reg < 4; ++reg) {
            int q = g * 4 + reg;
            int swz = (q & 7) << 3;
#pragma unroll
            for (int kg = 0; kg < 4; ++kg) {
                int key = lr + 16 * kg;
                Pw[q * 64 + (key ^ swz)] = f2b(s_acc[kg][reg]);
            }
        }
        int pswz = (lr & 7) << 3;
        short8 pa0 = *(const short8*)&Pw[lr * 64 + ((g * 8) ^ pswz)];
        short8 pa1 = *(const short8*)&Pw[lr * 64 + ((32 + g * 8) ^ pswz)];

#pragma unroll
        for (int dg = 0; dg < 4; ++dg) {
            int drow = dg * 16 + lr;
            int swz = (drow & 7) << 3;
            short8 vb0 = *(const short8*)&Vt[drow * 64 + ((g * 8) ^ swz)];
            short8 vb1 = *(const short8*)&Vt[drow * 64 + ((32 + g * 8) ^ swz)];
            acc[dg] = __builtin_amdgcn_mfma_f32_16x16x32_bf16(pa0, vb0, acc[dg], 0, 0, 0);
            acc[dg] = __builtin_amdgcn_mfma_f32_16x16x32_bf16(pa1, vb1, acc[dg], 0, 0, 0);
        }
    }

    unsigned short* O = out + (size_t)b * (1024 * 1024) + h * 64;
#pragma unroll
    for (int reg = 0; reg < 4; ++reg) {
        float inv = 1.0f / lsum[reg];
        int q = q0 + g * 4 + reg;
#pragma unroll
        for (int dg = 0; dg < 4; ++dg) {
            O[(size_t)q * 1024 + dg * 16 + lr] = f2b(acc[dg][reg] * inv);
        }
    }
}

// ---------------- launch ----------------
extern "C" void kernel_launch(void* const* d_in, const int* in_sizes, int n_in,
                              void* d_out, int out_size, void* d_ws, size_t ws_size,
                              hipStream_t stream) {
    const float* x = (const float*)d_in[0];
    const float* wq_w = (const float*)d_in[1];
    const float* wq_b = (const float*)d_in[2];
    const float* wo_w = (const float*)d_in[3];
    const float* wo_b = (const float*)d_in[4];
    const float* ff1_w = (const float*)d_in[5];
    const float* ff1_b = (const float*)d_in[6];
    const float* ff2_w = (const float*)d_in[7];
    const float* ff2_b = (const float*)d_in[8];
    const float* alpha1 = (const float*)d_in[9];
    const float* bias1 = (const float*)d_in[10];
    const float* alpha2 = (const float*)d_in[11];
    const float* bias2 = (const float*)d_in[12];
    const float* alpha3 = (const float*)d_in[13];
    const float* bias3 = (const float*)d_in[14];
    float* out = (float*)d_out;

    const size_t MB = 1u << 20;
    char* ws = (char*)d_ws;
    unsigned short* wq_t = (unsigned short*)(ws + 0 * MB);
    unsigned short* wo_t = (unsigned short*)(ws + 2 * MB);
    unsigned short* ff1_t = (unsigned short*)(ws + 4 * MB);
    unsigned short* ff2_t = (unsigned short*)(ws + 12 * MB);
    unsigned short* lnbuf = (unsigned short*)(ws + 20 * MB);
    unsigned short* pbuf = (unsigned short*)(ws + 28 * MB);
    unsigned short* attn = (unsigned short*)(ws + 36 * MB);
    float* h1 = (float*)(ws + 44 * MB);
    unsigned short* pbT = (unsigned short*)(ws + 60 * MB);
    unsigned short* mid = (unsigned short*)(ws + 60 * MB);
    float* h2 = (float*)(ws + 28 * MB);

    const int M = 4096;

    transpose_cast_kernel<<<dim3(32, 32), dim3(32, 8), 0, stream>>>(wq_w, wq_t, 1024, 1024);
    transpose_cast_kernel<<<dim3(32, 32), dim3(32, 8), 0, stream>>>(wo_w, wo_t, 1024, 1024);
    transpose_cast_kernel<<<dim3(128, 32), dim3(32, 8), 0, stream>>>(ff1_w, ff1_t, 1024, 4096);
    transpose_cast_kernel<<<dim3(32, 128), dim3(32, 8), 0, stream>>>(ff2_w, ff2_t, 4096, 1024);

    ln_kernel<true><<<M, 256, 0, stream>>>(x, lnbuf, alpha1, bias1);
    gemm2b<128, 64, false, false, true><<<512, 256, 0, stream>>>(lnbuf, wq_t, wq_b, nullptr, pbuf, M, 1024, 1024);
    transpose_bf16_batch<<<dim3(32, 32, 4), dim3(32, 8), 0, stream>>>(pbuf, pbT);
    attn_mfma_kernel<<<dim3(64, 16), 256, 0, stream>>>(pbuf, pbT, attn);
    gemm2b<128, 64, false, true, false><<<512, 256, 0, stream>>>(attn, wo_t, wo_b, x, h1, M, 1024, 1024);
    ln_kernel<true><<<M, 256, 0, stream>>>(h1, lnbuf, alpha2, bias2);
    gemm3<true, true><<<256, 512, 0, stream>>>(lnbuf, ff1_t, ff1_b, mid, M, 4096, 1024);
    gemm2b<128, 64, false, true, false><<<512, 256, 0, stream>>>(mid, ff2_t, ff2_b, h1, h2, M, 1024, 4096);
    ln_kernel<false><<<M, 256, 0, stream>>>(h2, out, alpha3, bias3);
}

// Round 13
// 232.974 us; speedup vs baseline: 1.1423x; 1.0784x over previous
//
#include <hip/hip_runtime.h>

typedef short short8 __attribute__((ext_vector_type(8)));
typedef float f32x4 __attribute__((ext_vector_type(4)));
typedef unsigned short u16x4 __attribute__((ext_vector_type(4)));

#define DEV static __device__ __forceinline__

DEV float b2f(unsigned short u) { return __uint_as_float(((unsigned)u) << 16); }
DEV unsigned short f2b(float f) {
    unsigned u = __float_as_uint(f);
    u += 0x7FFFu + ((u >> 16) & 1u);
    return (unsigned short)(u >> 16);
}
DEV float wred_sum(float v) {
#pragma unroll
    for (int o = 32; o; o >>= 1) v += __shfl_xor(v, o);
    return v;
}

DEV void gld_lds16(const unsigned short* g, unsigned short* l) {
    __builtin_amdgcn_global_load_lds((const __attribute__((address_space(1))) void*)g,
                                     (__attribute__((address_space(3))) void*)l, 16, 0, 0);
}

// ---------------- LayerNorm (standalone, for ln2/ln3) ----------------
template <bool OUT_BF16>
__global__ __launch_bounds__(256) void ln_kernel(const float* __restrict__ in,
                                                 void* __restrict__ out_v,
                                                 const float* __restrict__ alpha_p,
                                                 const float* __restrict__ bias_p) {
    __shared__ float redA[4], redB[4];
    const int row = blockIdx.x;
    const int t = threadIdx.x;
    const int lane = t & 63, w = t >> 6;

    f32x4 xv = *(const f32x4*)&in[(size_t)row * 1024 + t * 4];

    float s = wred_sum(xv[0] + xv[1] + xv[2] + xv[3]);
    if (lane == 0) redA[w] = s;
    __syncthreads();
    float mean = (redA[0] + redA[1] + redA[2] + redA[3]) * (1.0f / 1024.0f);

    float d0 = xv[0] - mean, d1 = xv[1] - mean, d2 = xv[2] - mean, d3 = xv[3] - mean;
    float ss = wred_sum(d0 * d0 + d1 * d1 + d2 * d2 + d3 * d3);
    if (lane == 0) redB[w] = ss;
    __syncthreads();
    float var = (redB[0] + redB[1] + redB[2] + redB[3]) * (1.0f / 1023.0f);
    float denom = sqrtf(var) + 1e-9f;
    float inv = alpha_p[0] / denom;
    float bias = bias_p[0];

    if (OUT_BF16) {
        u16x4 o;
        o[0] = f2b(d0 * inv + bias);
        o[1] = f2b(d1 * inv + bias);
        o[2] = f2b(d2 * inv + bias);
        o[3] = f2b(d3 * inv + bias);
        *(u16x4*)&((unsigned short*)out_v)[(size_t)row * 1024 + t * 4] = o;
    } else {
        f32x4 o;
        o[0] = d0 * inv + bias;
        o[1] = d1 * inv + bias;
        o[2] = d2 * inv + bias;
        o[3] = d3 * inv + bias;
        *(f32x4*)&((float*)out_v)[(size_t)row * 1024 + t * 4] = o;
    }
}

// ---------------- Fused prelude: LN1 (4096 blocks) + 4 weight transposes (10240 blocks) ----
__global__ __launch_bounds__(256) void prelude_kernel(
    const float* __restrict__ x, unsigned short* __restrict__ lnbuf,
    const float* __restrict__ alpha1, const float* __restrict__ bias1,
    const float* __restrict__ wq_w, unsigned short* __restrict__ wq_t,
    const float* __restrict__ wo_w, unsigned short* __restrict__ wo_t,
    const float* __restrict__ ff1_w, unsigned short* __restrict__ ff1_t,
    const float* __restrict__ ff2_w, unsigned short* __restrict__ ff2_t) {
    __shared__ unsigned short tile[32][33];
    __shared__ float redA[4], redB[4];
    const int t = threadIdx.x;
    int bid = blockIdx.x;

    if (bid < 4096) {
        // LN1 row
        const int row = bid;
        const int lane = t & 63, w = t >> 6;
        f32x4 xv = *(const f32x4*)&x[(size_t)row * 1024 + t * 4];
        float s = wred_sum(xv[0] + xv[1] + xv[2] + xv[3]);
        if (lane == 0) redA[w] = s;
        __syncthreads();
        float mean = (redA[0] + redA[1] + redA[2] + redA[3]) * (1.0f / 1024.0f);
        float d0 = xv[0] - mean, d1 = xv[1] - mean, d2 = xv[2] - mean, d3 = xv[3] - mean;
        float ss = wred_sum(d0 * d0 + d1 * d1 + d2 * d2 + d3 * d3);
        if (lane == 0) redB[w] = ss;
        __syncthreads();
        float var = (redB[0] + redB[1] + redB[2] + redB[3]) * (1.0f / 1023.0f);
        float inv = alpha1[0] / (sqrtf(var) + 1e-9f);
        float bias = bias1[0];
        u16x4 o;
        o[0] = f2b(d0 * inv + bias);
        o[1] = f2b(d1 * inv + bias);
        o[2] = f2b(d2 * inv + bias);
        o[3] = f2b(d3 * inv + bias);
        *(u16x4*)&lnbuf[(size_t)row * 1024 + t * 4] = o;
        return;
    }
    bid -= 4096;
    const float* src;
    unsigned short* dst;
    int R, C, gx;
    if (bid < 1024) {
        src = wq_w; dst = wq_t; R = 1024; C = 1024; gx = 32;
    } else if (bid < 2048) {
        bid -= 1024; src = wo_w; dst = wo_t; R = 1024; C = 1024; gx = 32;
    } else if (bid < 6144) {
        bid -= 2048; src = ff1_w; dst = ff1_t; R = 1024; C = 4096; gx = 128;
    } else {
        bid -= 6144; src = ff2_w; dst = ff2_t; R = 4096; C = 1024; gx = 32;
    }
    const int c0 = (bid % gx) * 32, r0 = (bid / gx) * 32;
    const int xx = t & 31, y0 = t >> 5;
#pragma unroll
    for (int yy = y0; yy < 32; yy += 8) tile[yy][xx] = f2b(src[(size_t)(r0 + yy) * C + c0 + xx]);
    __syncthreads();
#pragma unroll
    for (int yy = y0; yy < 32; yy += 8) dst[(size_t)(c0 + yy) * R + r0 + xx] = tile[xx][yy];
}

// ---------------- bf16 [b][s][d] -> [b][d][s] transpose ----------------
__global__ __launch_bounds__(256) void transpose_bf16_batch(const unsigned short* __restrict__ in,
                                                            unsigned short* __restrict__ out) {
    __shared__ unsigned short tile[32][33];
    const int b = blockIdx.z;
    const int d0 = blockIdx.x * 32, s0 = blockIdx.y * 32;
    const unsigned short* I = in + (size_t)b * 1024 * 1024;
    unsigned short* O = out + (size_t)b * 1024 * 1024;
    const int x = threadIdx.x, y0 = threadIdx.y;
#pragma unroll
    for (int yy = y0; yy < 32; yy += 8) tile[yy][x] = I[(size_t)(s0 + yy) * 1024 + d0 + x];
    __syncthreads();
#pragma unroll
    for (int yy = y0; yy < 32; yy += 8) O[(size_t)(d0 + yy) * 1024 + s0 + x] = tile[x][yy];
}

// ---------------- GEMM v2b: 128x64 tile, BK=64, RING-3 + counted vmcnt + raw barrier ----
template <int BM, int BN, bool RELU, bool RES, bool OUT_BF16>
__global__ __launch_bounds__(256) void gemm2b(const unsigned short* __restrict__ A,
                                              const unsigned short* __restrict__ Bt,
                                              const float* __restrict__ bias,
                                              const float* __restrict__ res,
                                              void* __restrict__ C_v,
                                              int M, int N, int K) {
    constexpr int WM = BM / 2, WN = BN / 2;
    constexpr int FM = WM / 16, FN = WN / 16;
    __shared__ __align__(16) unsigned short As[3][BM * 64];
    __shared__ __align__(16) unsigned short Bs[3][BN * 64];

    const int t = threadIdx.x;
    const int lane = t & 63, w = t >> 6;
    const int wr = w >> 1, wc = w & 1;
    const int lr = lane & 15, g = lane >> 4;

    const int nwg = gridDim.x;
    const int cpx = nwg >> 3;
    const int wg = blockIdx.x;
    const int swz = (wg & 7) * cpx + (wg >> 3);
    const int NB = N / BN;
    const int m0 = (swz / NB) * BM, n0 = (swz % NB) * BN;

    f32x4 acc[FM][FN];
#pragma unroll
    for (int i = 0; i < FM; ++i)
#pragma unroll
        for (int j = 0; j < FN; ++j) acc[i][j] = (f32x4)0.0f;

    const int NT = K / 64;

#define STAGE2B(kt)                                                                        \
    {                                                                                      \
        const int buf_ = (kt) % 3;                                                         \
        const int k0_ = (kt) * 64;                                                         \
        _Pragma("unroll") for (int i = 0; i < BM / 32; ++i) {                              \
            int id = i * 256 + t;                                                          \
            int row = id >> 3, ch = (id & 7) ^ (row & 7);                                  \
            gld_lds16(&A[(size_t)(m0 + row) * K + k0_ + ch * 8],                           \
                      &As[buf_][(size_t)(i * 256 + (t & ~63)) * 8]);                       \
        }                                                                                  \
        _Pragma("unroll") for (int i = 0; i < BN / 32; ++i) {                              \
            int id = i * 256 + t;                                                          \
            int row = id >> 3, ch = (id & 7) ^ (row & 7);                                  \
            gld_lds16(&Bt[(size_t)(n0 + row) * K + k0_ + ch * 8],                          \
                      &Bs[buf_][(size_t)(i * 256 + (t & ~63)) * 8]);                       \
        }                                                                                  \
    }

    STAGE2B(0);
    STAGE2B(1);
    asm volatile("s_waitcnt vmcnt(6)" ::: "memory");
    __builtin_amdgcn_sched_barrier(0);
    __builtin_amdgcn_s_barrier();

    for (int kt = 0; kt < NT; ++kt) {
        const int buf = kt % 3;
        if (kt + 2 < NT) STAGE2B(kt + 2);

        short8 af[FM][2], bfr[FN][2];
#pragma unroll
        for (int mi = 0; mi < FM; ++mi) {
            int row = wr * WM + mi * 16 + lr;
#pragma unroll
            for (int ks = 0; ks < 2; ++ks) {
                int ch = (ks * 4 + g) ^ (row & 7);
                af[mi][ks] = *(const short8*)&As[buf][row * 64 + ch * 8];
            }
        }
#pragma unroll
        for (int ni = 0; ni < FN; ++ni) {
            int row = wc * WN + ni * 16 + lr;
#pragma unroll
            for (int ks = 0; ks < 2; ++ks) {
                int ch = (ks * 4 + g) ^ (row & 7);
                bfr[ni][ks] = *(const short8*)&Bs[buf][row * 64 + ch * 8];
            }
        }

        __builtin_amdgcn_s_setprio(1);
#pragma unroll
        for (int ks = 0; ks < 2; ++ks)
#pragma unroll
            for (int mi = 0; mi < FM; ++mi)
#pragma unroll
                for (int ni = 0; ni < FN; ++ni)
                    acc[mi][ni] = __builtin_amdgcn_mfma_f32_16x16x32_bf16(af[mi][ks], bfr[ni][ks], acc[mi][ni], 0, 0, 0);
        __builtin_amdgcn_s_setprio(0);

        if (kt + 2 < NT) {
            asm volatile("s_waitcnt vmcnt(6)" ::: "memory");
        } else if (kt + 1 < NT) {
            asm volatile("s_waitcnt vmcnt(0)" ::: "memory");
        }
        __builtin_amdgcn_sched_barrier(0);
        __builtin_amdgcn_s_barrier();
    }
#undef STAGE2B

    const int lg = g;
#pragma unroll
    for (int ni = 0; ni < FN; ++ni) {
        int col = n0 + wc * WN + ni * 16 + lr;
        float bv = bias[col];
#pragma unroll
        for (int mi = 0; mi < FM; ++mi) {
            int row0 = m0 + wr * WM + mi * 16 + lg * 4;
#pragma unroll
            for (int i = 0; i < 4; ++i) {
                int row = row0 + i;
                float x = acc[mi][ni][i] + bv;
                if (RES) x += res[(size_t)row * N + col];
                if (RELU) x = fmaxf(x, 0.0f);
                if (OUT_BF16)
                    ((unsigned short*)C_v)[(size_t)row * N + col] = f2b(x);
                else
                    ((float*)C_v)[(size_t)row * N + col] = x;
            }
        }
    }
}

// ---------------- GEMM v3b: 256x128, BK=32, ring-3, 2 blocks/CU (FFN1) ----------------
// 512 threads = 8 waves (4M x 2N), wave output 64x64 (4x4 frags, 16 MFMA/ktile).
// STAGE = 3 gld_lds/thread (A 2 sweeps + B 1) -> vmcnt(3) waits exactly tile t+1.
// LDS 73.7 KB -> 2 blocks/CU -> 4 waves/SIMD (vs gemm3's 2).
template <bool RELU, bool OUT_BF16>
__global__ __launch_bounds__(512, 4) void gemm3b(const unsigned short* __restrict__ A,
                                                 const unsigned short* __restrict__ Bt,
                                                 const float* __restrict__ bias,
                                                 void* __restrict__ C_v,
                                                 int M, int N, int K) {
    __shared__ __align__(16) unsigned short As[3][256 * 32];
    __shared__ __align__(16) unsigned short Bs[3][128 * 32];

    const int t = threadIdx.x;
    const int lane = t & 63;
    const int wid = t >> 6;
    const int wr = wid >> 1, wc = wid & 1;
    const int lr = lane & 15, g = lane >> 4;

    const int nwg = gridDim.x;
    const int cpx = nwg >> 3;
    const int wg = blockIdx.x;
    const int swz = (wg & 7) * cpx + (wg >> 3);
    const int NB = N / 128;
    const int m0 = (swz / NB) * 256, n0 = (swz % NB) * 128;

    f32x4 acc[4][4];
#pragma unroll
    for (int i = 0; i < 4; ++i)
#pragma unroll
        for (int j = 0; j < 4; ++j) acc[i][j] = (f32x4)0.0f;

    const int NT = K / 32;

#define STAGE3B(kt)                                                                         \
    {                                                                                       \
        const int buf_ = (kt) % 3;                                                          \
        const int k0_ = (kt) * 32;                                                          \
        _Pragma("unroll") for (int s = 0; s < 2; ++s) {                                     \
            int id = s * 512 + t;                                                           \
            int row = id >> 2;                                                              \
            int ch = (id & 3) ^ ((row >> 1) & 3);                                           \
            gld_lds16(&A[(size_t)(m0 + row) * K + k0_ + ch * 8],                            \
                      &As[buf_][(size_t)(s * 512 + (t & ~63)) * 8]);                        \
        }                                                                                   \
        {                                                                                   \
            int row = t >> 2;                                                               \
            int ch = (t & 3) ^ ((row >> 1) & 3);                                            \
            gld_lds16(&Bt[(size_t)(n0 + row) * K + k0_ + ch * 8],                           \
                      &Bs[buf_][(size_t)(t & ~63) * 8]);                                    \
        }                                                                                   \
    }

    STAGE3B(0);
    STAGE3B(1);
    asm volatile("s_waitcnt vmcnt(3)" ::: "memory");
    __builtin_amdgcn_sched_barrier(0);
    __builtin_amdgcn_s_barrier();

    for (int kt = 0; kt < NT; ++kt) {
        const int buf = kt % 3;
        if (kt + 2 < NT) STAGE3B(kt + 2);

        short8 af[4], bf[4];
#pragma unroll
        for (int mi = 0; mi < 4; ++mi) {
            int row = wr * 64 + mi * 16 + lr;
            int ch = g ^ ((row >> 1) & 3);
            af[mi] = *(const short8*)&As[buf][row * 32 + ch * 8];
        }
#pragma unroll
        for (int nj = 0; nj < 4; ++nj) {
            int row = wc * 64 + nj * 16 + lr;
            int ch = g ^ ((row >> 1) & 3);
            bf[nj] = *(const short8*)&Bs[buf][row * 32 + ch * 8];
        }

        __builtin_amdgcn_s_setprio(1);
#pragma unroll
        for (int mi = 0; mi < 4; ++mi)
#pragma unroll
            for (int nj = 0; nj < 4; ++nj)
                acc[mi][nj] = __builtin_amdgcn_mfma_f32_16x16x32_bf16(af[mi], bf[nj], acc[mi][nj], 0, 0, 0);
        __builtin_amdgcn_s_setprio(0);

        if (kt + 2 < NT) {
            asm volatile("s_waitcnt vmcnt(3)" ::: "memory");
        } else if (kt + 1 < NT) {
            asm volatile("s_waitcnt vmcnt(0)" ::: "memory");
        }
        __builtin_amdgcn_sched_barrier(0);
        __builtin_amdgcn_s_barrier();
    }
#undef STAGE3B

#pragma unroll
    for (int nj = 0; nj < 4; ++nj) {
        int col = n0 + wc * 64 + nj * 16 + lr;
        float bv = bias[col];
#pragma unroll
        for (int mi = 0; mi < 4; ++mi) {
            int row0 = m0 + wr * 64 + mi * 16 + g * 4;
#pragma unroll
            for (int i = 0; i < 4; ++i) {
                int row = row0 + i;
                float x = acc[mi][nj][i] + bv;
                if (RELU) x = fmaxf(x, 0.0f);
                if (OUT_BF16)
                    ((unsigned short*)C_v)[(size_t)row * N + col] = f2b(x);
                else
                    ((float*)C_v)[(size_t)row * N + col] = x;
            }
        }
    }
}

// ---------------- MFMA flash attention (r4 structure, bh-major grid) ----------
__global__ __launch_bounds__(256) void attn_mfma_kernel(const unsigned short* __restrict__ p,
                                                        const unsigned short* __restrict__ pT,
                                                        unsigned short* __restrict__ out) {
    __shared__ __align__(16) unsigned short Ks[64 * 64];
    __shared__ __align__(16) unsigned short Vt[64 * 64];
    __shared__ __align__(16) unsigned short Ps[4 * 16 * 64];

    const int t = threadIdx.x;
    const int lane = t & 63, w = t >> 6;
    const int lr = lane & 15, g = lane >> 4;
    const int bh = blockIdx.x;
    const int qblk = blockIdx.y;
    const int b = bh >> 4, h = bh & 15;

    const unsigned short* Pm = p + (size_t)b * (1024 * 1024) + h * 64;
    const unsigned short* PT = pT + (size_t)b * (1024 * 1024) + (size_t)(h * 64) * 1024;

    const int q0 = qblk * 64 + w * 16;
    short8 qa0 = *(const short8*)&Pm[(size_t)(q0 + lr) * 1024 + g * 8];
    short8 qa1 = *(const short8*)&Pm[(size_t)(q0 + lr) * 1024 + 32 + g * 8];

    f32x4 acc[4];
#pragma unroll
    for (int i = 0; i < 4; ++i) acc[i] = (f32x4)0.0f;
    float mrow[4] = {-1e30f, -1e30f, -1e30f, -1e30f};
    float lsum[4] = {0.f, 0.f, 0.f, 0.f};

    unsigned short* Pw = &Ps[w * 16 * 64];

    for (int kt = 0; kt < 16; ++kt) {
        const int key0 = kt * 64;
        __syncthreads();
#pragma unroll
        for (int i = 0; i < 2; ++i) {
            int id = t + i * 256;
            int row = id >> 3, ch = (id & 7) * 8;
            int sw = ch ^ ((row & 7) << 3);
            short8 kv = *(const short8*)&Pm[(size_t)(key0 + row) * 1024 + ch];
            *(short8*)&Ks[row * 64 + sw] = kv;
            short8 vv = *(const short8*)&PT[(size_t)row * 1024 + key0 + ch];
            *(short8*)&Vt[row * 64 + sw] = vv;
        }
        __syncthreads();

        f32x4 s_acc[4];
#pragma unroll
        for (int kg = 0; kg < 4; ++kg) {
            s_acc[kg] = (f32x4)0.0f;
            int krow = kg * 16 + lr;
            int swz = (krow & 7) << 3;
            short8 kb0 = *(const short8*)&Ks[krow * 64 + ((g * 8) ^ swz)];
            short8 kb1 = *(const short8*)&Ks[krow * 64 + ((32 + g * 8) ^ swz)];
            s_acc[kg] = __builtin_amdgcn_mfma_f32_16x16x32_bf16(qa0, kb0, s_acc[kg], 0, 0, 0);
            s_acc[kg] = __builtin_amdgcn_mfma_f32_16x16x32_bf16(qa1, kb1, s_acc[kg], 0, 0, 0);
        }

#pragma unroll
        for (int reg = 0; reg < 4; ++reg) {
            float mx = fmaxf(fmaxf(s_acc[0][reg], s_acc[1][reg]),
                             fmaxf(s_acc[2][reg], s_acc[3][reg])) * 0.125f;
            mx = fmaxf(mx, __shfl_xor(mx, 1));
            mx = fmaxf(mx, __shfl_xor(mx, 2));
            mx = fmaxf(mx, __shfl_xor(mx, 4));
            mx = fmaxf(mx, __shfl_xor(mx, 8));
            float mnew = fmaxf(mrow[reg], mx);
            float scale = __expf(mrow[reg] - mnew);
            mrow[reg] = mnew;
            float psum = 0.f;
#pragma unroll
            for (int kg = 0; kg < 4; ++kg) {
                float pv = __expf(s_acc[kg][reg] * 0.125f - mnew);
                s_acc[kg][reg] = pv;
                psum += pv;
            }
            psum += __shfl_xor(psum, 1);
            psum += __shfl_xor(psum, 2);
            psum += __shfl_xor(psum, 4);
            psum += __shfl_xor(psum, 8);
            lsum[reg] = lsum[reg] * scale + psum;
#pragma unroll
            for (int dg = 0; dg < 4; ++dg) acc[dg][reg] *= scale;
        }

#pragma unroll
        for (int reg = 0; reg < 4; ++reg) {
            int q = g * 4 + reg;
            int swz = (q & 7) << 3;
#pragma unroll
            for (int kg = 0; kg < 4; ++kg) {
                int key = lr + 16 * kg;
                Pw[q * 64 + (key ^ swz)] = f2b(s_acc[kg][reg]);
            }
        }
        int pswz = (lr & 7) << 3;
        short8 pa0 = *(const short8*)&Pw[lr * 64 + ((g * 8) ^ pswz)];
        short8 pa1 = *(const short8*)&Pw[lr * 64 + ((32 + g * 8) ^ pswz)];

#pragma unroll
        for (int dg = 0; dg < 4; ++dg) {
            int drow = dg * 16 + lr;
            int swz = (drow & 7) << 3;
            short8 vb0 = *(const short8*)&Vt[drow * 64 + ((g * 8) ^ swz)];
            short8 vb1 = *(const short8*)&Vt[drow * 64 + ((32 + g * 8) ^ swz)];
            acc[dg] = __builtin_amdgcn_mfma_f32_16x16x32_bf16(pa0, vb0, acc[dg], 0, 0, 0);
            acc[dg] = __builtin_amdgcn_mfma_f32_16x16x32_bf16(pa1, vb1, acc[dg], 0, 0, 0);
        }
    }

    unsigned short* O = out + (size_t)b * (1024 * 1024) + h * 64;
#pragma unroll
    for (int reg = 0; reg < 4; ++reg) {
        float inv = 1.0f / lsum[reg];
        int q = q0 + g * 4 + reg;
#pragma unroll
        for (int dg = 0; dg < 4; ++dg) {
            O[(size_t)q * 1024 + dg * 16 + lr] = f2b(acc[dg][reg] * inv);
        }
    }
}

// ---------------- launch ----------------
extern "C" void kernel_launch(void* const* d_in, const int* in_sizes, int n_in,
                              void* d_out, int out_size, void* d_ws, size_t ws_size,
                              hipStream_t stream) {
    const float* x = (const float*)d_in[0];
    const float* wq_w = (const float*)d_in[1];
    const float* wq_b = (const float*)d_in[2];
    const float* wo_w = (const float*)d_in[3];
    const float* wo_b = (const float*)d_in[4];
    const float* ff1_w = (const float*)d_in[5];
    const float* ff1_b = (const float*)d_in[6];
    const float* ff2_w = (const float*)d_in[7];
    const float* ff2_b = (const float*)d_in[8];
    const float* alpha1 = (const float*)d_in[9];
    const float* bias1 = (const float*)d_in[10];
    const float* alpha2 = (const float*)d_in[11];
    const float* bias2 = (const float*)d_in[12];
    const float* alpha3 = (const float*)d_in[13];
    const float* bias3 = (const float*)d_in[14];
    float* out = (float*)d_out;

    const size_t MB = 1u << 20;
    char* ws = (char*)d_ws;
    unsigned short* wq_t = (unsigned short*)(ws + 0 * MB);
    unsigned short* wo_t = (unsigned short*)(ws + 2 * MB);
    unsigned short* ff1_t = (unsigned short*)(ws + 4 * MB);
    unsigned short* ff2_t = (unsigned short*)(ws + 12 * MB);
    unsigned short* lnbuf = (unsigned short*)(ws + 20 * MB);
    unsigned short* pbuf = (unsigned short*)(ws + 28 * MB);
    unsigned short* attn = (unsigned short*)(ws + 36 * MB);
    float* h1 = (float*)(ws + 44 * MB);
    unsigned short* pbT = (unsigned short*)(ws + 60 * MB);
    unsigned short* mid = (unsigned short*)(ws + 60 * MB);
    float* h2 = (float*)(ws + 28 * MB);

    const int M = 4096;

    // LN1 + all 4 weight transposes in ONE dispatch (independent inputs)
    prelude_kernel<<<14336, 256, 0, stream>>>(x, lnbuf, alpha1, bias1,
                                              wq_w, wq_t, wo_w, wo_t,
                                              ff1_w, ff1_t, ff2_w, ff2_t);
    gemm2b<128, 64, false, false, true><<<512, 256, 0, stream>>>(lnbuf, wq_t, wq_b, nullptr, pbuf, M, 1024, 1024);
    transpose_bf16_batch<<<dim3(32, 32, 4), dim3(32, 8), 0, stream>>>(pbuf, pbT);
    attn_mfma_kernel<<<dim3(64, 16), 256, 0, stream>>>(pbuf, pbT, attn);
    gemm2b<128, 64, false, true, false><<<512, 256, 0, stream>>>(attn, wo_t, wo_b, x, h1, M, 1024, 1024);
    ln_kernel<true><<<M, 256, 0, stream>>>(h1, lnbuf, alpha2, bias2);
    gemm3b<true, true><<<512, 512, 0, stream>>>(lnbuf, ff1_t, ff1_b, mid, M, 4096, 1024);
    gemm2b<128, 64, false, true, false><<<512, 256, 0, stream>>>(mid, ff2_t, ff2_b, h1, h2, M, 1024, 4096);
    ln_kernel<false><<<M, 256, 0, stream>>>(h2, out, alpha3, bias3);
}

// Round 14
// 226.350 us; speedup vs baseline: 1.1757x; 1.0293x over previous
//
#include <hip/hip_runtime.h>

typedef short short8 __attribute__((ext_vector_type(8)));
typedef float f32x4 __attribute__((ext_vector_type(4)));
typedef unsigned short u16x4 __attribute__((ext_vector_type(4)));

#define DEV static __device__ __forceinline__

DEV float b2f(unsigned short u) { return __uint_as_float(((unsigned)u) << 16); }
DEV unsigned short f2b(float f) {
    unsigned u = __float_as_uint(f);
    u += 0x7FFFu + ((u >> 16) & 1u);
    return (unsigned short)(u >> 16);
}
DEV float wred_sum(float v) {
#pragma unroll
    for (int o = 32; o; o >>= 1) v += __shfl_xor(v, o);
    return v;
}

DEV void gld_lds16(const unsigned short* g, unsigned short* l) {
    __builtin_amdgcn_global_load_lds((const __attribute__((address_space(1))) void*)g,
                                     (__attribute__((address_space(3))) void*)l, 16, 0, 0);
}

// ---------------- LayerNorm: f32 or bf16 in, f32 or bf16 out ----------------
template <bool IN_BF16, bool OUT_BF16>
__global__ __launch_bounds__(256) void ln_kernel(const void* __restrict__ in_v,
                                                 void* __restrict__ out_v,
                                                 const float* __restrict__ alpha_p,
                                                 const float* __restrict__ bias_p) {
    __shared__ float redA[4], redB[4];
    const int row = blockIdx.x;
    const int t = threadIdx.x;
    const int lane = t & 63, w = t >> 6;

    float x0, x1, x2, x3;
    if (IN_BF16) {
        u16x4 raw = *(const u16x4*)&((const unsigned short*)in_v)[(size_t)row * 1024 + t * 4];
        x0 = b2f(raw[0]); x1 = b2f(raw[1]); x2 = b2f(raw[2]); x3 = b2f(raw[3]);
    } else {
        f32x4 xv = *(const f32x4*)&((const float*)in_v)[(size_t)row * 1024 + t * 4];
        x0 = xv[0]; x1 = xv[1]; x2 = xv[2]; x3 = xv[3];
    }

    float s = wred_sum(x0 + x1 + x2 + x3);
    if (lane == 0) redA[w] = s;
    __syncthreads();
    float mean = (redA[0] + redA[1] + redA[2] + redA[3]) * (1.0f / 1024.0f);

    float d0 = x0 - mean, d1 = x1 - mean, d2 = x2 - mean, d3 = x3 - mean;
    float ss = wred_sum(d0 * d0 + d1 * d1 + d2 * d2 + d3 * d3);
    if (lane == 0) redB[w] = ss;
    __syncthreads();
    float var = (redB[0] + redB[1] + redB[2] + redB[3]) * (1.0f / 1023.0f);
    float denom = sqrtf(var) + 1e-9f;
    float inv = alpha_p[0] / denom;
    float bias = bias_p[0];

    if (OUT_BF16) {
        u16x4 o;
        o[0] = f2b(d0 * inv + bias);
        o[1] = f2b(d1 * inv + bias);
        o[2] = f2b(d2 * inv + bias);
        o[3] = f2b(d3 * inv + bias);
        *(u16x4*)&((unsigned short*)out_v)[(size_t)row * 1024 + t * 4] = o;
    } else {
        f32x4 o;
        o[0] = d0 * inv + bias;
        o[1] = d1 * inv + bias;
        o[2] = d2 * inv + bias;
        o[3] = d3 * inv + bias;
        *(f32x4*)&((float*)out_v)[(size_t)row * 1024 + t * 4] = o;
    }
}

// ---------------- Fused prelude: LN1 (4096 blocks) + 4 weight transposes (10240 blocks) ----
__global__ __launch_bounds__(256) void prelude_kernel(
    const float* __restrict__ x, unsigned short* __restrict__ lnbuf,
    const float* __restrict__ alpha1, const float* __restrict__ bias1,
    const float* __restrict__ wq_w, unsigned short* __restrict__ wq_t,
    const float* __restrict__ wo_w, unsigned short* __restrict__ wo_t,
    const float* __restrict__ ff1_w, unsigned short* __restrict__ ff1_t,
    const float* __restrict__ ff2_w, unsigned short* __restrict__ ff2_t) {
    __shared__ unsigned short tile[32][33];
    __shared__ float redA[4], redB[4];
    const int t = threadIdx.x;
    int bid = blockIdx.x;

    if (bid < 4096) {
        const int row = bid;
        const int lane = t & 63, w = t >> 6;
        f32x4 xv = *(const f32x4*)&x[(size_t)row * 1024 + t * 4];
        float s = wred_sum(xv[0] + xv[1] + xv[2] + xv[3]);
        if (lane == 0) redA[w] = s;
        __syncthreads();
        float mean = (redA[0] + redA[1] + redA[2] + redA[3]) * (1.0f / 1024.0f);
        float d0 = xv[0] - mean, d1 = xv[1] - mean, d2 = xv[2] - mean, d3 = xv[3] - mean;
        float ss = wred_sum(d0 * d0 + d1 * d1 + d2 * d2 + d3 * d3);
        if (lane == 0) redB[w] = ss;
        __syncthreads();
        float var = (redB[0] + redB[1] + redB[2] + redB[3]) * (1.0f / 1023.0f);
        float inv = alpha1[0] / (sqrtf(var) + 1e-9f);
        float bias = bias1[0];
        u16x4 o;
        o[0] = f2b(d0 * inv + bias);
        o[1] = f2b(d1 * inv + bias);
        o[2] = f2b(d2 * inv + bias);
        o[3] = f2b(d3 * inv + bias);
        *(u16x4*)&lnbuf[(size_t)row * 1024 + t * 4] = o;
        return;
    }
    bid -= 4096;
    const float* src;
    unsigned short* dst;
    int R, C, gx;
    if (bid < 1024) {
        src = wq_w; dst = wq_t; R = 1024; C = 1024; gx = 32;
    } else if (bid < 2048) {
        bid -= 1024; src = wo_w; dst = wo_t; R = 1024; C = 1024; gx = 32;
    } else if (bid < 6144) {
        bid -= 2048; src = ff1_w; dst = ff1_t; R = 1024; C = 4096; gx = 128;
    } else {
        bid -= 6144; src = ff2_w; dst = ff2_t; R = 4096; C = 1024; gx = 32;
    }
    const int c0 = (bid % gx) * 32, r0 = (bid / gx) * 32;
    const int xx = t & 31, y0 = t >> 5;
#pragma unroll
    for (int yy = y0; yy < 32; yy += 8) tile[yy][xx] = f2b(src[(size_t)(r0 + yy) * C + c0 + xx]);
    __syncthreads();
#pragma unroll
    for (int yy = y0; yy < 32; yy += 8) dst[(size_t)(c0 + yy) * R + r0 + xx] = tile[xx][yy];
}

// ---------------- GEMM v2b: 128x64 tile, BK=64, RING-3 + counted vmcnt + raw barrier ----
// RES_MODE: 0 none, 1 f32 residual, 2 bf16 residual. WRITE_T: also write C^T (per-batch
// [b][d][s] layout, for attention V^T) via 8B packed stores (requires OUT_BF16).
template <int BM, int BN, bool RELU, int RES_MODE, bool OUT_BF16, bool WRITE_T>
__global__ __launch_bounds__(256) void gemm2b(const unsigned short* __restrict__ A,
                                              const unsigned short* __restrict__ Bt,
                                              const float* __restrict__ bias,
                                              const void* __restrict__ res,
                                              void* __restrict__ C_v,
                                              unsigned short* __restrict__ Ct,
                                              int M, int N, int K) {
    constexpr int WM = BM / 2, WN = BN / 2;
    constexpr int FM = WM / 16, FN = WN / 16;
    __shared__ __align__(16) unsigned short As[3][BM * 64];
    __shared__ __align__(16) unsigned short Bs[3][BN * 64];

    const int t = threadIdx.x;
    const int lane = t & 63, w = t >> 6;
    const int wr = w >> 1, wc = w & 1;
    const int lr = lane & 15, g = lane >> 4;

    const int nwg = gridDim.x;
    const int cpx = nwg >> 3;
    const int wg = blockIdx.x;
    const int swz = (wg & 7) * cpx + (wg >> 3);
    const int NB = N / BN;
    const int m0 = (swz / NB) * BM, n0 = (swz % NB) * BN;

    f32x4 acc[FM][FN];
#pragma unroll
    for (int i = 0; i < FM; ++i)
#pragma unroll
        for (int j = 0; j < FN; ++j) acc[i][j] = (f32x4)0.0f;

    const int NT = K / 64;

#define STAGE2B(kt)                                                                        \
    {                                                                                      \
        const int buf_ = (kt) % 3;                                                         \
        const int k0_ = (kt) * 64;                                                         \
        _Pragma("unroll") for (int i = 0; i < BM / 32; ++i) {                              \
            int id = i * 256 + t;                                                          \
            int row = id >> 3, ch = (id & 7) ^ (row & 7);                                  \
            gld_lds16(&A[(size_t)(m0 + row) * K + k0_ + ch * 8],                           \
                      &As[buf_][(size_t)(i * 256 + (t & ~63)) * 8]);                       \
        }                                                                                  \
        _Pragma("unroll") for (int i = 0; i < BN / 32; ++i) {                              \
            int id = i * 256 + t;                                                          \
            int row = id >> 3, ch = (id & 7) ^ (row & 7);                                  \
            gld_lds16(&Bt[(size_t)(n0 + row) * K + k0_ + ch * 8],                          \
                      &Bs[buf_][(size_t)(i * 256 + (t & ~63)) * 8]);                       \
        }                                                                                  \
    }

    STAGE2B(0);
    STAGE2B(1);
    asm volatile("s_waitcnt vmcnt(6)" ::: "memory");
    __builtin_amdgcn_sched_barrier(0);
    __builtin_amdgcn_s_barrier();

    for (int kt = 0; kt < NT; ++kt) {
        const int buf = kt % 3;
        if (kt + 2 < NT) STAGE2B(kt + 2);

        short8 af[FM][2], bfr[FN][2];
#pragma unroll
        for (int mi = 0; mi < FM; ++mi) {
            int row = wr * WM + mi * 16 + lr;
#pragma unroll
            for (int ks = 0; ks < 2; ++ks) {
                int ch = (ks * 4 + g) ^ (row & 7);
                af[mi][ks] = *(const short8*)&As[buf][row * 64 + ch * 8];
            }
        }
#pragma unroll
        for (int ni = 0; ni < FN; ++ni) {
            int row = wc * WN + ni * 16 + lr;
#pragma unroll
            for (int ks = 0; ks < 2; ++ks) {
                int ch = (ks * 4 + g) ^ (row & 7);
                bfr[ni][ks] = *(const short8*)&Bs[buf][row * 64 + ch * 8];
            }
        }

        __builtin_amdgcn_s_setprio(1);
#pragma unroll
        for (int ks = 0; ks < 2; ++ks)
#pragma unroll
            for (int mi = 0; mi < FM; ++mi)
#pragma unroll
                for (int ni = 0; ni < FN; ++ni)
                    acc[mi][ni] = __builtin_amdgcn_mfma_f32_16x16x32_bf16(af[mi][ks], bfr[ni][ks], acc[mi][ni], 0, 0, 0);
        __builtin_amdgcn_s_setprio(0);

        if (kt + 2 < NT) {
            asm volatile("s_waitcnt vmcnt(6)" ::: "memory");
        } else if (kt + 1 < NT) {
            asm volatile("s_waitcnt vmcnt(0)" ::: "memory");
        }
        __builtin_amdgcn_sched_barrier(0);
        __builtin_amdgcn_s_barrier();
    }
#undef STAGE2B

    const int lg = g;
#pragma unroll
    for (int ni = 0; ni < FN; ++ni) {
        int col = n0 + wc * WN + ni * 16 + lr;
        float bv = bias[col];
#pragma unroll
        for (int mi = 0; mi < FM; ++mi) {
            int row0 = m0 + wr * WM + mi * 16 + lg * 4;
            u16x4 tv;
#pragma unroll
            for (int i = 0; i < 4; ++i) {
                int row = row0 + i;
                float x = acc[mi][ni][i] + bv;
                if (RES_MODE == 1) x += ((const float*)res)[(size_t)row * N + col];
                if (RES_MODE == 2) x += b2f(((const unsigned short*)res)[(size_t)row * N + col]);
                if (RELU) x = fmaxf(x, 0.0f);
                if (OUT_BF16) {
                    unsigned short v = f2b(x);
                    ((unsigned short*)C_v)[(size_t)row * N + col] = v;
                    if (WRITE_T) tv[i] = v;
                } else {
                    ((float*)C_v)[(size_t)row * N + col] = x;
                }
            }
            if (WRITE_T) {
                int bb = row0 >> 10, s = row0 & 1023;
                *(u16x4*)&Ct[(size_t)bb * (1024 * 1024) + (size_t)col * 1024 + s] = tv;
            }
        }
    }
}

// ---------------- GEMM v3b: 256x128, BK=32, ring-3, 2 blocks/CU (FFN1) ----------------
template <bool RELU, bool OUT_BF16>
__global__ __launch_bounds__(512, 4) void gemm3b(const unsigned short* __restrict__ A,
                                                 const unsigned short* __restrict__ Bt,
                                                 const float* __restrict__ bias,
                                                 void* __restrict__ C_v,
                                                 int M, int N, int K) {
    __shared__ __align__(16) unsigned short As[3][256 * 32];
    __shared__ __align__(16) unsigned short Bs[3][128 * 32];

    const int t = threadIdx.x;
    const int lane = t & 63;
    const int wid = t >> 6;
    const int wr = wid >> 1, wc = wid & 1;
    const int lr = lane & 15, g = lane >> 4;

    const int nwg = gridDim.x;
    const int cpx = nwg >> 3;
    const int wg = blockIdx.x;
    const int swz = (wg & 7) * cpx + (wg >> 3);
    const int NB = N / 128;
    const int m0 = (swz / NB) * 256, n0 = (swz % NB) * 128;

    f32x4 acc[4][4];
#pragma unroll
    for (int i = 0; i < 4; ++i)
#pragma unroll
        for (int j = 0; j < 4; ++j) acc[i][j] = (f32x4)0.0f;

    const int NT = K / 32;

#define STAGE3B(kt)                                                                         \
    {                                                                                       \
        const int buf_ = (kt) % 3;                                                          \
        const int k0_ = (kt) * 32;                                                          \
        _Pragma("unroll") for (int s = 0; s < 2; ++s) {                                     \
            int id = s * 512 + t;                                                           \
            int row = id >> 2;                                                              \
            int ch = (id & 3) ^ ((row >> 1) & 3);                                           \
            gld_lds16(&A[(size_t)(m0 + row) * K + k0_ + ch * 8],                            \
                      &As[buf_][(size_t)(s * 512 + (t & ~63)) * 8]);                        \
        }                                                                                   \
        {                                                                                   \
            int row = t >> 2;                                                               \
            int ch = (t & 3) ^ ((row >> 1) & 3);                                            \
            gld_lds16(&Bt[(size_t)(n0 + row) * K + k0_ + ch * 8],                           \
                      &Bs[buf_][(size_t)(t & ~63) * 8]);                                    \
        }                                                                                   \
    }

    STAGE3B(0);
    STAGE3B(1);
    asm volatile("s_waitcnt vmcnt(3)" ::: "memory");
    __builtin_amdgcn_sched_barrier(0);
    __builtin_amdgcn_s_barrier();

    for (int kt = 0; kt < NT; ++kt) {
        const int buf = kt % 3;
        if (kt + 2 < NT) STAGE3B(kt + 2);

        short8 af[4], bf[4];
#pragma unroll
        for (int mi = 0; mi < 4; ++mi) {
            int row = wr * 64 + mi * 16 + lr;
            int ch = g ^ ((row >> 1) & 3);
            af[mi] = *(const short8*)&As[buf][row * 32 + ch * 8];
        }
#pragma unroll
        for (int nj = 0; nj < 4; ++nj) {
            int row = wc * 64 + nj * 16 + lr;
            int ch = g ^ ((row >> 1) & 3);
            bf[nj] = *(const short8*)&Bs[buf][row * 32 + ch * 8];
        }

        __builtin_amdgcn_s_setprio(1);
#pragma unroll
        for (int mi = 0; mi < 4; ++mi)
#pragma unroll
            for (int nj = 0; nj < 4; ++nj)
                acc[mi][nj] = __builtin_amdgcn_mfma_f32_16x16x32_bf16(af[mi], bf[nj], acc[mi][nj], 0, 0, 0);
        __builtin_amdgcn_s_setprio(0);

        if (kt + 2 < NT) {
            asm volatile("s_waitcnt vmcnt(3)" ::: "memory");
        } else if (kt + 1 < NT) {
            asm volatile("s_waitcnt vmcnt(0)" ::: "memory");
        }
        __builtin_amdgcn_sched_barrier(0);
        __builtin_amdgcn_s_barrier();
    }
#undef STAGE3B

#pragma unroll
    for (int nj = 0; nj < 4; ++nj) {
        int col = n0 + wc * 64 + nj * 16 + lr;
        float bv = bias[col];
#pragma unroll
        for (int mi = 0; mi < 4; ++mi) {
            int row0 = m0 + wr * 64 + mi * 16 + g * 4;
#pragma unroll
            for (int i = 0; i < 4; ++i) {
                int row = row0 + i;
                float x = acc[mi][nj][i] + bv;
                if (RELU) x = fmaxf(x, 0.0f);
                if (OUT_BF16)
                    ((unsigned short*)C_v)[(size_t)row * N + col] = f2b(x);
                else
                    ((float*)C_v)[(size_t)row * N + col] = x;
            }
        }
    }
}

// ---------------- MFMA flash attention (r4 structure, bh-major grid) ----------
__global__ __launch_bounds__(256) void attn_mfma_kernel(const unsigned short* __restrict__ p,
                                                        const unsigned short* __restrict__ pT,
                                                        unsigned short* __restrict__ out) {
    __shared__ __align__(16) unsigned short Ks[64 * 64];
    __shared__ __align__(16) unsigned short Vt[64 * 64];
    __shared__ __align__(16) unsigned short Ps[4 * 16 * 64];

    const int t = threadIdx.x;
    const int lane = t & 63, w = t >> 6;
    const int lr = lane & 15, g = lane >> 4;
    const int bh = blockIdx.x;
    const int qblk = blockIdx.y;
    const int b = bh >> 4, h = bh & 15;

    const unsigned short* Pm = p + (size_t)b * (1024 * 1024) + h * 64;
    const unsigned short* PT = pT + (size_t)b * (1024 * 1024) + (size_t)(h * 64) * 1024;

    const int q0 = qblk * 64 + w * 16;
    short8 qa0 = *(const short8*)&Pm[(size_t)(q0 + lr) * 1024 + g * 8];
    short8 qa1 = *(const short8*)&Pm[(size_t)(q0 + lr) * 1024 + 32 + g * 8];

    f32x4 acc[4];
#pragma unroll
    for (int i = 0; i < 4; ++i) acc[i] = (f32x4)0.0f;
    float mrow[4] = {-1e30f, -1e30f, -1e30f, -1e30f};
    float lsum[4] = {0.f, 0.f, 0.f, 0.f};

    unsigned short* Pw = &Ps[w * 16 * 64];

    for (int kt = 0; kt < 16; ++kt) {
        const int key0 = kt * 64;
        __syncthreads();
#pragma unroll
        for (int i = 0; i < 2; ++i) {
            int id = t + i * 256;
            int row = id >> 3, ch = (id & 7) * 8;
            int sw = ch ^ ((row & 7) << 3);
            short8 kv = *(const short8*)&Pm[(size_t)(key0 + row) * 1024 + ch];
            *(short8*)&Ks[row * 64 + sw] = kv;
            short8 vv = *(const short8*)&PT[(size_t)row * 1024 + key0 + ch];
            *(short8*)&Vt[row * 64 + sw] = vv;
        }
        __syncthreads();

        f32x4 s_acc[4];
#pragma unroll
        for (int kg = 0; kg < 4; ++kg) {
            s_acc[kg] = (f32x4)0.0f;
            int krow = kg * 16 + lr;
            int swz = (krow & 7) << 3;
            short8 kb0 = *(const short8*)&Ks[krow * 64 + ((g * 8) ^ swz)];
            short8 kb1 = *(const short8*)&Ks[krow * 64 + ((32 + g * 8) ^ swz)];
            s_acc[kg] = __builtin_amdgcn_mfma_f32_16x16x32_bf16(qa0, kb0, s_acc[kg], 0, 0, 0);
            s_acc[kg] = __builtin_amdgcn_mfma_f32_16x16x32_bf16(qa1, kb1, s_acc[kg], 0, 0, 0);
        }

#pragma unroll
        for (int reg = 0; reg < 4; ++reg) {
            float mx = fmaxf(fmaxf(s_acc[0][reg], s_acc[1][reg]),
                             fmaxf(s_acc[2][reg], s_acc[3][reg])) * 0.125f;
            mx = fmaxf(mx, __shfl_xor(mx, 1));
            mx = fmaxf(mx, __shfl_xor(mx, 2));
            mx = fmaxf(mx, __shfl_xor(mx, 4));
            mx = fmaxf(mx, __shfl_xor(mx, 8));
            float mnew = fmaxf(mrow[reg], mx);
            float scale = __expf(mrow[reg] - mnew);
            mrow[reg] = mnew;
            float psum = 0.f;
#pragma unroll
            for (int kg = 0; kg < 4; ++kg) {
                float pv = __expf(s_acc[kg][reg] * 0.125f - mnew);
                s_acc[kg][reg] = pv;
                psum += pv;
            }
            psum += __shfl_xor(psum, 1);
            psum += __shfl_xor(psum, 2);
            psum += __shfl_xor(psum, 4);
            psum += __shfl_xor(psum, 8);
            lsum[reg] = lsum[reg] * scale + psum;
#pragma unroll
            for (int dg = 0; dg < 4; ++dg) acc[dg][reg] *= scale;
        }

#pragma unroll
        for (int reg = 0; reg < 4; ++reg) {
            int q = g * 4 + reg;
            int swz = (q & 7) << 3;
#pragma unroll
            for (int kg = 0; kg < 4; ++kg) {
                int key = lr + 16 * kg;
                Pw[q * 64 + (key ^ swz)] = f2b(s_acc[kg][reg]);
            }
        }
        int pswz = (lr & 7) << 3;
        short8 pa0 = *(const short8*)&Pw[lr * 64 + ((g * 8) ^ pswz)];
        short8 pa1 = *(const short8*)&Pw[lr * 64 + ((32 + g * 8) ^ pswz)];

#pragma unroll
        for (int dg = 0; dg < 4; ++dg) {
            int drow = dg * 16 + lr;
            int swz = (drow & 7) << 3;
            short8 vb0 = *(const short8*)&Vt[drow * 64 + ((g * 8) ^ swz)];
            short8 vb1 = *(const short8*)&Vt[drow * 64 + ((32 + g * 8) ^ swz)];
            acc[dg] = __builtin_amdgcn_mfma_f32_16x16x32_bf16(pa0, vb0, acc[dg], 0, 0, 0);
            acc[dg] = __builtin_amdgcn_mfma_f32_16x16x32_bf16(pa1, vb1, acc[dg], 0, 0, 0);
        }
    }

    unsigned short* O = out + (size_t)b * (1024 * 1024) + h * 64;
#pragma unroll
    for (int reg = 0; reg < 4; ++reg) {
        float inv = 1.0f / lsum[reg];
        int q = q0 + g * 4 + reg;
#pragma unroll
        for (int dg = 0; dg < 4; ++dg) {
            O[(size_t)q * 1024 + dg * 16 + lr] = f2b(acc[dg][reg] * inv);
        }
    }
}

// ---------------- launch ----------------
extern "C" void kernel_launch(void* const* d_in, const int* in_sizes, int n_in,
                              void* d_out, int out_size, void* d_ws, size_t ws_size,
                              hipStream_t stream) {
    const float* x = (const float*)d_in[0];
    const float* wq_w = (const float*)d_in[1];
    const float* wq_b = (const float*)d_in[2];
    const float* wo_w = (const float*)d_in[3];
    const float* wo_b = (const float*)d_in[4];
    const float* ff1_w = (const float*)d_in[5];
    const float* ff1_b = (const float*)d_in[6];
    const float* ff2_w = (const float*)d_in[7];
    const float* ff2_b = (const float*)d_in[8];
    const float* alpha1 = (const float*)d_in[9];
    const float* bias1 = (const float*)d_in[10];
    const float* alpha2 = (const float*)d_in[11];
    const float* bias2 = (const float*)d_in[12];
    const float* alpha3 = (const float*)d_in[13];
    const float* bias3 = (const float*)d_in[14];
    float* out = (float*)d_out;

    const size_t MB = 1u << 20;
    char* ws = (char*)d_ws;
    unsigned short* wq_t = (unsigned short*)(ws + 0 * MB);
    unsigned short* wo_t = (unsigned short*)(ws + 2 * MB);
    unsigned short* ff1_t = (unsigned short*)(ws + 4 * MB);
    unsigned short* ff2_t = (unsigned short*)(ws + 12 * MB);
    unsigned short* lnbuf = (unsigned short*)(ws + 20 * MB);
    unsigned short* pbuf = (unsigned short*)(ws + 28 * MB);
    unsigned short* attn = (unsigned short*)(ws + 36 * MB);
    unsigned short* h1 = (unsigned short*)(ws + 44 * MB);   // bf16 now
    unsigned short* h2 = (unsigned short*)(ws + 52 * MB);   // bf16 now
    unsigned short* pbT = (unsigned short*)(ws + 60 * MB);
    unsigned short* mid = (unsigned short*)(ws + 60 * MB);

    const int M = 4096;

    prelude_kernel<<<14336, 256, 0, stream>>>(x, lnbuf, alpha1, bias1,
                                              wq_w, wq_t, wo_w, wo_t,
                                              ff1_w, ff1_t, ff2_w, ff2_t);
    // p = ln1 @ wq + b; also write pT (fused transpose)
    gemm2b<128, 64, false, 0, true, true><<<512, 256, 0, stream>>>(lnbuf, wq_t, wq_b, nullptr, pbuf, pbT, M, 1024, 1024);
    attn_mfma_kernel<<<dim3(64, 16), 256, 0, stream>>>(pbuf, pbT, attn);
    // h1 = x(f32) + attn @ wo + b -> bf16
    gemm2b<128, 64, false, 1, true, false><<<512, 256, 0, stream>>>(attn, wo_t, wo_b, x, h1, nullptr, M, 1024, 1024);
    ln_kernel<true, true><<<M, 256, 0, stream>>>(h1, lnbuf, alpha2, bias2);
    gemm3b<true, true><<<512, 512, 0, stream>>>(lnbuf, ff1_t, ff1_b, mid, M, 4096, 1024);
    // h2 = h1(bf16) + mid @ ff2 + b -> bf16
    gemm2b<128, 64, false, 2, true, false><<<512, 256, 0, stream>>>(mid, ff2_t, ff2_b, h1, h2, nullptr, M, 1024, 4096);
    ln_kernel<true, false><<<M, 256, 0, stream>>>(h2, out, alpha3, bias3);
}